// Round 1
// baseline (1108.598 us; speedup 1.0000x reference)
//
#include <hip/hip_runtime.h>
#include <hip/hip_bf16.h>

#define BATCH 8
#define LSEQ 2048
#define DDIM 512

using f32x4 = __attribute__((ext_vector_type(4))) float;
using s16x8 = __attribute__((ext_vector_type(8))) short;

static __device__ __forceinline__ unsigned short f2b(float f) {
  __hip_bfloat16 h = __float2bfloat16(f);
  return __builtin_bit_cast(unsigned short, h);
}
static __device__ __forceinline__ float b2f(unsigned short u) {
  unsigned int v = ((unsigned int)u) << 16;
  return __builtin_bit_cast(float, v);
}

#define LP 40  // LDS row stride (bf16 elems) for 32-wide K tile, padded (80B: 2-way bank alias = free)

// Generic 128x128-tile bf16 MFMA GEMM K-loop.
// A row-major (m,k) with leading dim lda; Bt row-major (n,k) leading dim ldb.
// 256 threads = 4 waves, each wave owns a 64x64 subtile (4x4 frags of 16x16x32).
__device__ __forceinline__ void mfma_kloop(
    const unsigned short* __restrict__ A, const unsigned short* __restrict__ Bt,
    int K, int lda, int ldb, unsigned short* sA, unsigned short* sB,
    int tid, f32x4 acc[4][4]) {
  const int wave = tid >> 6, lane = tid & 63;
  const int wm = (wave >> 1) * 64, wn = (wave & 1) * 64;
  const int lr = lane & 15, lq = lane >> 4;
  const int srow = tid >> 2;       // 0..63
  const int sk = (tid & 3) * 8;    // 0,8,16,24
  for (int k0 = 0; k0 < K; k0 += 32) {
    uint4 va0 = *(const uint4*)(A + (size_t)srow * lda + k0 + sk);
    uint4 va1 = *(const uint4*)(A + (size_t)(srow + 64) * lda + k0 + sk);
    uint4 vb0 = *(const uint4*)(Bt + (size_t)srow * ldb + k0 + sk);
    uint4 vb1 = *(const uint4*)(Bt + (size_t)(srow + 64) * ldb + k0 + sk);
    *(uint4*)(sA + srow * LP + sk) = va0;
    *(uint4*)(sA + (srow + 64) * LP + sk) = va1;
    *(uint4*)(sB + srow * LP + sk) = vb0;
    *(uint4*)(sB + (srow + 64) * LP + sk) = vb1;
    __syncthreads();
    s16x8 af[4], bf[4];
#pragma unroll
    for (int r = 0; r < 4; ++r)
      af[r] = *(const s16x8*)(sA + (wm + r * 16 + lr) * LP + lq * 8);
#pragma unroll
    for (int c = 0; c < 4; ++c)
      bf[c] = *(const s16x8*)(sB + (wn + c * 16 + lr) * LP + lq * 8);
#pragma unroll
    for (int r = 0; r < 4; ++r)
#pragma unroll
      for (int c = 0; c < 4; ++c)
        acc[r][c] = __builtin_amdgcn_mfma_f32_16x16x32_bf16(af[r], bf[c], acc[r][c], 0, 0, 0);
    __syncthreads();
  }
}

// f32 -> bf16 bulk convert, 4 elems/thread
__global__ __launch_bounds__(256) void k_f2b(const float* __restrict__ in,
                                             unsigned short* __restrict__ out) {
  int idx = blockIdx.x * 256 + threadIdx.x;
  float4 v = ((const float4*)in)[idx];
  ushort4 o;
  o.x = f2b(v.x); o.y = f2b(v.y); o.z = f2b(v.z); o.w = f2b(v.w);
  ((ushort4*)out)[idx] = o;
}

// W [D,H] f32 -> WT [H,D] bf16 (small, 1MB read; coalesced writes)
__global__ __launch_bounds__(256) void k_transposeW(const float* __restrict__ W,
                                                    unsigned short* __restrict__ WT) {
  int idx = blockIdx.x * 256 + threadIdx.x;  // h*512 + d
  int h = idx >> 9, d = idx & 511;
  WT[idx] = f2b(W[d * DDIM + h]);
}

// C[b,d] = (1/L) * sum_{l: mask[b,l]==0} in[b,l,d]
__global__ __launch_bounds__(256) void k_maskedmean(const float* __restrict__ in,
                                                    const int* __restrict__ mask,
                                                    float* __restrict__ C) {
  int b = blockIdx.y;
  int d0 = blockIdx.x * 128;
  int dl = threadIdx.x & 127, half = threadIdx.x >> 7;
  __shared__ float part[256];
  float s = 0.f;
  for (int l = half; l < LSEQ; l += 2) {
    if (mask[b * LSEQ + l] == 0)
      s += in[((size_t)b * LSEQ + l) * DDIM + d0 + dl];
  }
  part[threadIdx.x] = s;
  __syncthreads();
  if (half == 0) C[b * DDIM + d0 + dl] = (part[dl] + part[128 + dl]) * (1.0f / LSEQ);
}

// mapped = A(bf16) @ W^T(bf16) + bias, output bf16. A: [16384,512], Bt: [512,512].
__global__ __launch_bounds__(256) void k_gemm_bias(const unsigned short* __restrict__ A,
                                                   const unsigned short* __restrict__ Bt,
                                                   const float* __restrict__ bias,
                                                   unsigned short* __restrict__ Cout) {
  __shared__ unsigned short sA[128 * LP], sB[128 * LP];
  f32x4 acc[4][4];
  f32x4 zero = {0.f, 0.f, 0.f, 0.f};
#pragma unroll
  for (int r = 0; r < 4; ++r)
#pragma unroll
    for (int c = 0; c < 4; ++c) acc[r][c] = zero;
  int bm = blockIdx.y * 128, bn = blockIdx.x * 128;
  mfma_kloop(A + (size_t)bm * DDIM, Bt + (size_t)bn * DDIM, DDIM, DDIM, DDIM,
             sA, sB, threadIdx.x, acc);
  int wave = threadIdx.x >> 6, lane = threadIdx.x & 63;
  int wm = (wave >> 1) * 64, wn = (wave & 1) * 64, lr = lane & 15, lq = lane >> 4;
#pragma unroll
  for (int r = 0; r < 4; ++r)
#pragma unroll
    for (int c = 0; c < 4; ++c)
#pragma unroll
      for (int rr = 0; rr < 4; ++rr) {
        int row = bm + wm + r * 16 + lq * 4 + rr;
        int col = bn + wn + c * 16 + lr;
        Cout[(size_t)row * DDIM + col] = f2b(acc[r][c][rr] + bias[col]);
      }
}

// S = mapped_a @ mapped_b^T per batch; E = mask ? exp(S*scale) : 0 (bf16),
// written both row-major (E) and transposed (ET, via LDS).
__global__ __launch_bounds__(256) void k_scores(const unsigned short* __restrict__ mapa,
                                                const unsigned short* __restrict__ mapb,
                                                const int* __restrict__ mask_a,
                                                const int* __restrict__ mask_b,
                                                unsigned short* __restrict__ E,
                                                unsigned short* __restrict__ ET) {
  __shared__ unsigned short sA[128 * LP], sB[128 * LP];
  __shared__ unsigned short sT[128 * 136];  // [j][i], stride 136 (16B-aligned rows)
  __shared__ int sMa[128], sMb[128];
  int b = blockIdx.z;
  int bi = blockIdx.y * 128, bj = blockIdx.x * 128;
  if (threadIdx.x < 128)
    sMa[threadIdx.x] = mask_a[b * LSEQ + bi + threadIdx.x];
  else
    sMb[threadIdx.x - 128] = mask_b[b * LSEQ + bj + threadIdx.x - 128];
  f32x4 acc[4][4];
  f32x4 zero = {0.f, 0.f, 0.f, 0.f};
#pragma unroll
  for (int r = 0; r < 4; ++r)
#pragma unroll
    for (int c = 0; c < 4; ++c) acc[r][c] = zero;
  const unsigned short* Ab = mapa + ((size_t)b * LSEQ + bi) * DDIM;
  const unsigned short* Bb = mapb + ((size_t)b * LSEQ + bj) * DDIM;
  mfma_kloop(Ab, Bb, DDIM, DDIM, DDIM, sA, sB, threadIdx.x, acc);
  const float scale = 0.044194173824159216f;  // 1/sqrt(512)
  unsigned short* Eb = E + (size_t)b * LSEQ * LSEQ;
  unsigned short* ETb = ET + (size_t)b * LSEQ * LSEQ;
  int wave = threadIdx.x >> 6, lane = threadIdx.x & 63;
  int wm = (wave >> 1) * 64, wn = (wave & 1) * 64, lr = lane & 15, lq = lane >> 4;
#pragma unroll
  for (int r = 0; r < 4; ++r)
#pragma unroll
    for (int c = 0; c < 4; ++c)
#pragma unroll
      for (int rr = 0; rr < 4; ++rr) {
        int il = wm + r * 16 + lq * 4 + rr;
        int jl = wn + c * 16 + lr;
        float e = (sMa[il] && sMb[jl]) ? __expf(acc[r][c][rr] * scale) : 0.f;
        unsigned short eu = f2b(e);
        Eb[(size_t)(bi + il) * LSEQ + (bj + jl)] = eu;
        sT[jl * 136 + il] = eu;
      }
  __syncthreads();
  int jrow = threadIdx.x >> 1, cbase = (threadIdx.x & 1) * 64;
#pragma unroll
  for (int p = 0; p < 8; ++p) {
    uint4 v = *(const uint4*)(sT + jrow * 136 + cbase + p * 8);
    *(uint4*)(ETb + (size_t)(bj + jrow) * LSEQ + bi + cbase + p * 8) = v;
  }
}

// Z[row] = sum of 2048 bf16 entries of one row. One wave per row.
__global__ __launch_bounds__(64) void k_rowsum(const unsigned short* __restrict__ Ein,
                                               float* __restrict__ Z) {
  const unsigned short* row = Ein + (size_t)blockIdx.x * LSEQ;
  float s = 0.f;
#pragma unroll
  for (int p = 0; p < 4; ++p) {
    uint4 v = *(const uint4*)(row + p * 512 + threadIdx.x * 8);
    unsigned int w[4] = {v.x, v.y, v.z, v.w};
#pragma unroll
    for (int q = 0; q < 4; ++q) {
      s += b2f((unsigned short)(w[q] & 0xffffu));
      s += b2f((unsigned short)(w[q] >> 16));
    }
  }
#pragma unroll
  for (int off = 32; off > 0; off >>= 1) s += __shfl_down(s, off);
  if (threadIdx.x == 0) Z[blockIdx.x] = s;
}

// out[b,d,i] = (Z[b,i]>0 ? 1/Z[b,i] : 0) * in[b,i,d], bf16, transposed store.
__global__ __launch_bounds__(256) void k_scaleT(const float* __restrict__ in,
                                                const float* __restrict__ Z,
                                                unsigned short* __restrict__ out) {
  int b = blockIdx.z;
  int i0 = blockIdx.y * 64, d0 = blockIdx.x * 64;
  __shared__ unsigned short lt[64 * 65];
  __shared__ float zinv[64];
  if (threadIdx.x < 64) {
    float z = Z[b * LSEQ + i0 + threadIdx.x];
    zinv[threadIdx.x] = (z > 0.f) ? 1.f / z : 0.f;
  }
  __syncthreads();
  const float* ib = in + ((size_t)b * LSEQ + i0) * DDIM + d0;
#pragma unroll
  for (int p = 0; p < 16; ++p) {
    int idx = p * 256 + threadIdx.x;
    int dl = idx & 63, il = idx >> 6;
    lt[dl * 65 + il] = f2b(ib[(size_t)il * DDIM + dl] * zinv[il]);
  }
  __syncthreads();
  unsigned short* ob = out + ((size_t)b * DDIM + d0) * LSEQ + i0;
#pragma unroll
  for (int p = 0; p < 16; ++p) {
    int idx = p * 256 + threadIdx.x;
    int il = idx & 63, dl = idx >> 6;
    ob[(size_t)dl * LSEQ + il] = lt[dl * 65 + il];
  }
}

// Out[b,m,d] = (Eop @ Sop^T)[m,d] + addin[b,m,d] + Cvec[b,d]
// Eop: [B,2048,2048] bf16 (A, k contig); Sop: [B,512,2048] bf16 (Bt, k contig).
__global__ __launch_bounds__(256) void k_gemm_out(const unsigned short* __restrict__ Eop,
                                                  const unsigned short* __restrict__ Sop,
                                                  const float* __restrict__ addin,
                                                  const float* __restrict__ Cvec,
                                                  float* __restrict__ Out) {
  __shared__ unsigned short sA[128 * LP], sB[128 * LP];
  int b = blockIdx.z;
  int bm = blockIdx.y * 128, bn = blockIdx.x * 128;
  f32x4 acc[4][4];
  f32x4 zero = {0.f, 0.f, 0.f, 0.f};
#pragma unroll
  for (int r = 0; r < 4; ++r)
#pragma unroll
    for (int c = 0; c < 4; ++c) acc[r][c] = zero;
  mfma_kloop(Eop + (size_t)b * LSEQ * LSEQ + (size_t)bm * LSEQ,
             Sop + (size_t)b * DDIM * LSEQ + (size_t)bn * LSEQ,
             LSEQ, LSEQ, LSEQ, sA, sB, threadIdx.x, acc);
  int wave = threadIdx.x >> 6, lane = threadIdx.x & 63;
  int wm = (wave >> 1) * 64, wn = (wave & 1) * 64, lr = lane & 15, lq = lane >> 4;
#pragma unroll
  for (int r = 0; r < 4; ++r)
#pragma unroll
    for (int c = 0; c < 4; ++c)
#pragma unroll
      for (int rr = 0; rr < 4; ++rr) {
        int row = bm + wm + r * 16 + lq * 4 + rr;
        int col = bn + wn + c * 16 + lr;
        size_t o = ((size_t)b * LSEQ + row) * DDIM + col;
        Out[o] = acc[r][c][rr] + addin[o] + Cvec[b * DDIM + col];
      }
}

extern "C" void kernel_launch(void* const* d_in, const int* in_sizes, int n_in,
                              void* d_out, int out_size, void* d_ws, size_t ws_size,
                              hipStream_t stream) {
  (void)in_sizes; (void)n_in; (void)out_size; (void)ws_size;
  const float* in_a = (const float*)d_in[0];
  const float* in_b = (const float*)d_in[1];
  const int* ma = (const int*)d_in[2];
  const int* mb = (const int*)d_in[3];
  const float* Wa = (const float*)d_in[4];
  const float* ba = (const float*)d_in[5];
  const float* Wb = (const float*)d_in[6];
  const float* bb = (const float*)d_in[7];
  float* out = (float*)d_out;

  char* ws = (char*)d_ws;
  const size_t MB = 1ull << 20;
  unsigned short* a16 = (unsigned short*)(ws + 0 * MB);    // 16MB (reused as atS later)
  unsigned short* b16 = (unsigned short*)(ws + 16 * MB);   // 16MB (reused as btS later)
  unsigned short* WaT = (unsigned short*)(ws + 32 * MB);   // 0.5MB
  unsigned short* WbT = (unsigned short*)(ws + 32 * MB + 512 * 1024);
  unsigned short* mapa = (unsigned short*)(ws + 33 * MB);  // 16MB
  unsigned short* mapb = (unsigned short*)(ws + 49 * MB);  // 16MB
  unsigned short* E = (unsigned short*)(ws + 65 * MB);     // 64MB
  unsigned short* ET = (unsigned short*)(ws + 129 * MB);   // 64MB
  float* Zrow = (float*)(ws + 193 * MB);                   // 64KB
  float* Zcol = (float*)(ws + 193 * MB + 65536);           // 64KB
  float* Ca = (float*)(ws + 193 * MB + 2 * 65536);         // 16KB
  float* Cb = (float*)(ws + 193 * MB + 2 * 65536 + 16384); // 16KB
  unsigned short* atS = a16;  // [B,512,2048] scaled-transposed input_a
  unsigned short* btS = b16;  // [B,512,2048] scaled-transposed input_b

  k_f2b<<<8192, 256, 0, stream>>>(in_a, a16);
  k_f2b<<<8192, 256, 0, stream>>>(in_b, b16);
  k_transposeW<<<1024, 256, 0, stream>>>(Wa, WaT);
  k_transposeW<<<1024, 256, 0, stream>>>(Wb, WbT);
  k_maskedmean<<<dim3(4, 8), 256, 0, stream>>>(in_a, ma, Ca);
  k_maskedmean<<<dim3(4, 8), 256, 0, stream>>>(in_b, mb, Cb);
  k_gemm_bias<<<dim3(4, 128), 256, 0, stream>>>(a16, WaT, ba, mapa);
  k_gemm_bias<<<dim3(4, 128), 256, 0, stream>>>(b16, WbT, bb, mapb);
  k_scores<<<dim3(16, 16, 8), 256, 0, stream>>>(mapa, mapb, ma, mb, E, ET);
  k_rowsum<<<16384, 64, 0, stream>>>(E, Zrow);
  k_rowsum<<<16384, 64, 0, stream>>>(ET, Zcol);
  k_scaleT<<<dim3(8, 32, 8), 256, 0, stream>>>(in_a, Zrow, atS);
  k_scaleT<<<dim3(8, 32, 8), 256, 0, stream>>>(in_b, Zcol, btS);
  k_gemm_out<<<dim3(4, 16, 8), 256, 0, stream>>>(E, btS, in_a, Cb, out);
  k_gemm_out<<<dim3(4, 16, 8), 256, 0, stream>>>(ET, atS, in_b, Ca,
                                                 out + (size_t)BATCH * LSEQ * DDIM);
}

// Round 2
// 469.931 us; speedup vs baseline: 2.3591x; 2.3591x over previous
//
#include <hip/hip_runtime.h>
#include <hip/hip_bf16.h>

#define BATCH 8
#define LSEQ 2048
#define DDIM 512

using f32x4 = __attribute__((ext_vector_type(4))) float;
using s16x8 = __attribute__((ext_vector_type(8))) short;

static __device__ __forceinline__ unsigned short f2b(float f) {
  __hip_bfloat16 h = __float2bfloat16(f);
  return __builtin_bit_cast(unsigned short, h);
}
static __device__ __forceinline__ float b2f(unsigned short u) {
  unsigned int v = ((unsigned int)u) << 16;
  return __builtin_bit_cast(float, v);
}

#define LP 40  // LDS row stride (bf16 elems) for 32-wide K tile, padded (80B: 2-way bank alias = free)

// Generic 128x128-tile bf16 MFMA GEMM K-loop.
// A row-major (m,k) with leading dim lda; Bt row-major (n,k) leading dim ldb.
// 256 threads = 4 waves, each wave owns a 64x64 subtile (4x4 frags of 16x16x32).
__device__ __forceinline__ void mfma_kloop(
    const unsigned short* __restrict__ A, const unsigned short* __restrict__ Bt,
    int K, int lda, int ldb, unsigned short* sA, unsigned short* sB,
    int tid, f32x4 acc[4][4]) {
  const int wave = tid >> 6, lane = tid & 63;
  const int wm = (wave >> 1) * 64, wn = (wave & 1) * 64;
  const int lr = lane & 15, lq = lane >> 4;
  const int srow = tid >> 2;       // 0..63
  const int sk = (tid & 3) * 8;    // 0,8,16,24
  for (int k0 = 0; k0 < K; k0 += 32) {
    uint4 va0 = *(const uint4*)(A + (size_t)srow * lda + k0 + sk);
    uint4 va1 = *(const uint4*)(A + (size_t)(srow + 64) * lda + k0 + sk);
    uint4 vb0 = *(const uint4*)(Bt + (size_t)srow * ldb + k0 + sk);
    uint4 vb1 = *(const uint4*)(Bt + (size_t)(srow + 64) * ldb + k0 + sk);
    *(uint4*)(sA + srow * LP + sk) = va0;
    *(uint4*)(sA + (srow + 64) * LP + sk) = va1;
    *(uint4*)(sB + srow * LP + sk) = vb0;
    *(uint4*)(sB + (srow + 64) * LP + sk) = vb1;
    __syncthreads();
    s16x8 af[4], bf[4];
#pragma unroll
    for (int r = 0; r < 4; ++r)
      af[r] = *(const s16x8*)(sA + (wm + r * 16 + lr) * LP + lq * 8);
#pragma unroll
    for (int c = 0; c < 4; ++c)
      bf[c] = *(const s16x8*)(sB + (wn + c * 16 + lr) * LP + lq * 8);
#pragma unroll
    for (int r = 0; r < 4; ++r)
#pragma unroll
      for (int c = 0; c < 4; ++c)
        acc[r][c] = __builtin_amdgcn_mfma_f32_16x16x32_bf16(af[r], bf[c], acc[r][c], 0, 0, 0);
    __syncthreads();
  }
}

// f32 -> bf16 bulk convert, 4 elems/thread
__global__ __launch_bounds__(256) void k_f2b(const float* __restrict__ in,
                                             unsigned short* __restrict__ out) {
  int idx = blockIdx.x * 256 + threadIdx.x;
  float4 v = ((const float4*)in)[idx];
  ushort4 o;
  o.x = f2b(v.x); o.y = f2b(v.y); o.z = f2b(v.z); o.w = f2b(v.w);
  ((ushort4*)out)[idx] = o;
}

// W [D,H] f32 -> WT [H,D] bf16 (small, 1MB read; coalesced writes)
__global__ __launch_bounds__(256) void k_transposeW(const float* __restrict__ W,
                                                    unsigned short* __restrict__ WT) {
  int idx = blockIdx.x * 256 + threadIdx.x;  // h*512 + d
  int h = idx >> 9, d = idx & 511;
  WT[idx] = f2b(W[d * DDIM + h]);
}

// Stage 1: partial[b,chunk,d] = sum over 32 rows of chunk where mask==0.
// 512 blocks, fully coalesced float2 reads; mask branch is block-uniform.
__global__ __launch_bounds__(256) void k_maskedmean_p1(const float* __restrict__ in,
                                                       const int* __restrict__ mask,
                                                       float* __restrict__ partial) {
  int b = blockIdx.y;
  int l0 = blockIdx.x * 32;
  __shared__ int sm[32];
  if (threadIdx.x < 32) sm[threadIdx.x] = mask[b * LSEQ + l0 + threadIdx.x];
  __syncthreads();
  int d = threadIdx.x * 2;
  const float* base = in + ((size_t)b * LSEQ + l0) * DDIM + d;
  float ax = 0.f, ay = 0.f;
#pragma unroll 4
  for (int r = 0; r < 32; ++r) {
    if (sm[r] == 0) {
      float2 v = *(const float2*)(base + (size_t)r * DDIM);
      ax += v.x; ay += v.y;
    }
  }
  float2 o; o.x = ax; o.y = ay;
  *(float2*)(partial + ((size_t)(b * 64 + blockIdx.x)) * DDIM + d) = o;
}

// Stage 2: C[b,d] = (1/L) * sum over 64 partials.
__global__ __launch_bounds__(256) void k_maskedmean_p2(const float* __restrict__ partial,
                                                       float* __restrict__ C) {
  int b = blockIdx.x;
  int d = threadIdx.x * 2;
  float ax = 0.f, ay = 0.f;
  for (int c = 0; c < 64; ++c) {
    float2 v = *(const float2*)(partial + ((size_t)(b * 64 + c)) * DDIM + d);
    ax += v.x; ay += v.y;
  }
  C[b * DDIM + d] = ax * (1.0f / LSEQ);
  C[b * DDIM + d + 1] = ay * (1.0f / LSEQ);
}

// mapped = A(bf16) @ W^T(bf16) + bias, output bf16. A: [16384,512], Bt: [512,512].
__global__ __launch_bounds__(256) void k_gemm_bias(const unsigned short* __restrict__ A,
                                                   const unsigned short* __restrict__ Bt,
                                                   const float* __restrict__ bias,
                                                   unsigned short* __restrict__ Cout) {
  __shared__ unsigned short sA[128 * LP], sB[128 * LP];
  f32x4 acc[4][4];
  f32x4 zero = {0.f, 0.f, 0.f, 0.f};
#pragma unroll
  for (int r = 0; r < 4; ++r)
#pragma unroll
    for (int c = 0; c < 4; ++c) acc[r][c] = zero;
  int bm = blockIdx.y * 128, bn = blockIdx.x * 128;
  mfma_kloop(A + (size_t)bm * DDIM, Bt + (size_t)bn * DDIM, DDIM, DDIM, DDIM,
             sA, sB, threadIdx.x, acc);
  int wave = threadIdx.x >> 6, lane = threadIdx.x & 63;
  int wm = (wave >> 1) * 64, wn = (wave & 1) * 64, lr = lane & 15, lq = lane >> 4;
#pragma unroll
  for (int r = 0; r < 4; ++r)
#pragma unroll
    for (int c = 0; c < 4; ++c)
#pragma unroll
      for (int rr = 0; rr < 4; ++rr) {
        int row = bm + wm + r * 16 + lq * 4 + rr;
        int col = bn + wn + c * 16 + lr;
        Cout[(size_t)row * DDIM + col] = f2b(acc[r][c][rr] + bias[col]);
      }
}

// S = mapped_a @ mapped_b^T per batch; E = mask ? exp(S*scale) : 0 (bf16),
// written both row-major (E) and transposed (ET, via LDS).
__global__ __launch_bounds__(256) void k_scores(const unsigned short* __restrict__ mapa,
                                                const unsigned short* __restrict__ mapb,
                                                const int* __restrict__ mask_a,
                                                const int* __restrict__ mask_b,
                                                unsigned short* __restrict__ E,
                                                unsigned short* __restrict__ ET) {
  __shared__ unsigned short sA[128 * LP], sB[128 * LP];
  __shared__ unsigned short sT[128 * 136];  // [j][i], stride 136 (16B-aligned rows)
  __shared__ int sMa[128], sMb[128];
  int b = blockIdx.z;
  int bi = blockIdx.y * 128, bj = blockIdx.x * 128;
  if (threadIdx.x < 128)
    sMa[threadIdx.x] = mask_a[b * LSEQ + bi + threadIdx.x];
  else
    sMb[threadIdx.x - 128] = mask_b[b * LSEQ + bj + threadIdx.x - 128];
  f32x4 acc[4][4];
  f32x4 zero = {0.f, 0.f, 0.f, 0.f};
#pragma unroll
  for (int r = 0; r < 4; ++r)
#pragma unroll
    for (int c = 0; c < 4; ++c) acc[r][c] = zero;
  const unsigned short* Ab = mapa + ((size_t)b * LSEQ + bi) * DDIM;
  const unsigned short* Bb = mapb + ((size_t)b * LSEQ + bj) * DDIM;
  mfma_kloop(Ab, Bb, DDIM, DDIM, DDIM, sA, sB, threadIdx.x, acc);
  const float scale = 0.044194173824159216f;  // 1/sqrt(512)
  unsigned short* Eb = E + (size_t)b * LSEQ * LSEQ;
  unsigned short* ETb = ET + (size_t)b * LSEQ * LSEQ;
  int wave = threadIdx.x >> 6, lane = threadIdx.x & 63;
  int wm = (wave >> 1) * 64, wn = (wave & 1) * 64, lr = lane & 15, lq = lane >> 4;
#pragma unroll
  for (int r = 0; r < 4; ++r)
#pragma unroll
    for (int c = 0; c < 4; ++c)
#pragma unroll
      for (int rr = 0; rr < 4; ++rr) {
        int il = wm + r * 16 + lq * 4 + rr;
        int jl = wn + c * 16 + lr;
        float e = (sMa[il] && sMb[jl]) ? __expf(acc[r][c][rr] * scale) : 0.f;
        unsigned short eu = f2b(e);
        Eb[(size_t)(bi + il) * LSEQ + (bj + jl)] = eu;
        sT[jl * 136 + il] = eu;
      }
  __syncthreads();
  int jrow = threadIdx.x >> 1, cbase = (threadIdx.x & 1) * 64;
#pragma unroll
  for (int p = 0; p < 8; ++p) {
    uint4 v = *(const uint4*)(sT + jrow * 136 + cbase + p * 8);
    *(uint4*)(ETb + (size_t)(bj + jrow) * LSEQ + bi + cbase + p * 8) = v;
  }
}

// Z[row] = sum of 2048 bf16 entries of one row. One wave per row.
__global__ __launch_bounds__(64) void k_rowsum(const unsigned short* __restrict__ Ein,
                                               float* __restrict__ Z) {
  const unsigned short* row = Ein + (size_t)blockIdx.x * LSEQ;
  float s = 0.f;
#pragma unroll
  for (int p = 0; p < 4; ++p) {
    uint4 v = *(const uint4*)(row + p * 512 + threadIdx.x * 8);
    unsigned int w[4] = {v.x, v.y, v.z, v.w};
#pragma unroll
    for (int q = 0; q < 4; ++q) {
      s += b2f((unsigned short)(w[q] & 0xffffu));
      s += b2f((unsigned short)(w[q] >> 16));
    }
  }
#pragma unroll
  for (int off = 32; off > 0; off >>= 1) s += __shfl_down(s, off);
  if (threadIdx.x == 0) Z[blockIdx.x] = s;
}

// out[b,d,i] = (Z[b,i]>0 ? 1/Z[b,i] : 0) * in[b,i,d], bf16, transposed store.
__global__ __launch_bounds__(256) void k_scaleT(const float* __restrict__ in,
                                                const float* __restrict__ Z,
                                                unsigned short* __restrict__ out) {
  int b = blockIdx.z;
  int i0 = blockIdx.y * 64, d0 = blockIdx.x * 64;
  __shared__ unsigned short lt[64 * 65];
  __shared__ float zinv[64];
  if (threadIdx.x < 64) {
    float z = Z[b * LSEQ + i0 + threadIdx.x];
    zinv[threadIdx.x] = (z > 0.f) ? 1.f / z : 0.f;
  }
  __syncthreads();
  const float* ib = in + ((size_t)b * LSEQ + i0) * DDIM + d0;
#pragma unroll
  for (int p = 0; p < 16; ++p) {
    int idx = p * 256 + threadIdx.x;
    int dl = idx & 63, il = idx >> 6;
    lt[dl * 65 + il] = f2b(ib[(size_t)il * DDIM + dl] * zinv[il]);
  }
  __syncthreads();
  unsigned short* ob = out + ((size_t)b * DDIM + d0) * LSEQ + i0;
#pragma unroll
  for (int p = 0; p < 16; ++p) {
    int idx = p * 256 + threadIdx.x;
    int il = idx & 63, dl = idx >> 6;
    ob[(size_t)dl * LSEQ + il] = lt[dl * 65 + il];
  }
}

// Out[b,m,d] = (Eop @ Sop^T)[m,d] + addin[b,m,d] + Cvec[b,d]
// Eop: [B,2048,2048] bf16 (A, k contig); Sop: [B,512,2048] bf16 (Bt, k contig).
__global__ __launch_bounds__(256) void k_gemm_out(const unsigned short* __restrict__ Eop,
                                                  const unsigned short* __restrict__ Sop,
                                                  const float* __restrict__ addin,
                                                  const float* __restrict__ Cvec,
                                                  float* __restrict__ Out) {
  __shared__ unsigned short sA[128 * LP], sB[128 * LP];
  int b = blockIdx.z;
  int bm = blockIdx.y * 128, bn = blockIdx.x * 128;
  f32x4 acc[4][4];
  f32x4 zero = {0.f, 0.f, 0.f, 0.f};
#pragma unroll
  for (int r = 0; r < 4; ++r)
#pragma unroll
    for (int c = 0; c < 4; ++c) acc[r][c] = zero;
  mfma_kloop(Eop + (size_t)b * LSEQ * LSEQ + (size_t)bm * LSEQ,
             Sop + (size_t)b * DDIM * LSEQ + (size_t)bn * LSEQ,
             LSEQ, LSEQ, LSEQ, sA, sB, threadIdx.x, acc);
  int wave = threadIdx.x >> 6, lane = threadIdx.x & 63;
  int wm = (wave >> 1) * 64, wn = (wave & 1) * 64, lr = lane & 15, lq = lane >> 4;
#pragma unroll
  for (int r = 0; r < 4; ++r)
#pragma unroll
    for (int c = 0; c < 4; ++c)
#pragma unroll
      for (int rr = 0; rr < 4; ++rr) {
        int row = bm + wm + r * 16 + lq * 4 + rr;
        int col = bn + wn + c * 16 + lr;
        size_t o = ((size_t)b * LSEQ + row) * DDIM + col;
        Out[o] = acc[r][c][rr] + addin[o] + Cvec[b * DDIM + col];
      }
}

extern "C" void kernel_launch(void* const* d_in, const int* in_sizes, int n_in,
                              void* d_out, int out_size, void* d_ws, size_t ws_size,
                              hipStream_t stream) {
  (void)in_sizes; (void)n_in; (void)out_size; (void)ws_size;
  const float* in_a = (const float*)d_in[0];
  const float* in_b = (const float*)d_in[1];
  const int* ma = (const int*)d_in[2];
  const int* mb = (const int*)d_in[3];
  const float* Wa = (const float*)d_in[4];
  const float* ba = (const float*)d_in[5];
  const float* Wb = (const float*)d_in[6];
  const float* bb = (const float*)d_in[7];
  float* out = (float*)d_out;

  char* ws = (char*)d_ws;
  const size_t MB = 1ull << 20;
  unsigned short* a16 = (unsigned short*)(ws + 0 * MB);    // 16MB (reused as atS later)
  unsigned short* b16 = (unsigned short*)(ws + 16 * MB);   // 16MB (reused as btS later)
  unsigned short* WaT = (unsigned short*)(ws + 32 * MB);   // 0.5MB
  unsigned short* WbT = (unsigned short*)(ws + 32 * MB + 512 * 1024);
  unsigned short* mapa = (unsigned short*)(ws + 33 * MB);  // 16MB
  unsigned short* mapb = (unsigned short*)(ws + 49 * MB);  // 16MB
  unsigned short* E = (unsigned short*)(ws + 65 * MB);     // 64MB
  unsigned short* ET = (unsigned short*)(ws + 129 * MB);   // 64MB
  float* Zrow = (float*)(ws + 193 * MB);                   // 64KB
  float* Zcol = (float*)(ws + 193 * MB + 65536);           // 64KB
  float* Ca = (float*)(ws + 193 * MB + 2 * 65536);         // 16KB
  float* Cb = (float*)(ws + 193 * MB + 2 * 65536 + 16384); // 16KB
  float* Pmm = (float*)(ws + 193 * MB + 2 * 65536 + 2 * 16384);  // 1MB partials
  unsigned short* atS = a16;  // [B,512,2048] scaled-transposed input_a
  unsigned short* btS = b16;  // [B,512,2048] scaled-transposed input_b

  k_f2b<<<8192, 256, 0, stream>>>(in_a, a16);
  k_f2b<<<8192, 256, 0, stream>>>(in_b, b16);
  k_transposeW<<<1024, 256, 0, stream>>>(Wa, WaT);
  k_transposeW<<<1024, 256, 0, stream>>>(Wb, WbT);
  k_maskedmean_p1<<<dim3(64, 8), 256, 0, stream>>>(in_a, ma, Pmm);
  k_maskedmean_p2<<<8, 256, 0, stream>>>(Pmm, Ca);
  k_maskedmean_p1<<<dim3(64, 8), 256, 0, stream>>>(in_b, mb, Pmm);
  k_maskedmean_p2<<<8, 256, 0, stream>>>(Pmm, Cb);
  k_gemm_bias<<<dim3(4, 128), 256, 0, stream>>>(a16, WaT, ba, mapa);
  k_gemm_bias<<<dim3(4, 128), 256, 0, stream>>>(b16, WbT, bb, mapb);
  k_scores<<<dim3(16, 16, 8), 256, 0, stream>>>(mapa, mapb, ma, mb, E, ET);
  k_rowsum<<<16384, 64, 0, stream>>>(E, Zrow);
  k_rowsum<<<16384, 64, 0, stream>>>(ET, Zcol);
  k_scaleT<<<dim3(8, 32, 8), 256, 0, stream>>>(in_a, Zrow, atS);
  k_scaleT<<<dim3(8, 32, 8), 256, 0, stream>>>(in_b, Zcol, btS);
  k_gemm_out<<<dim3(4, 16, 8), 256, 0, stream>>>(E, btS, in_a, Cb, out);
  k_gemm_out<<<dim3(4, 16, 8), 256, 0, stream>>>(ET, atS, in_b, Ca,
                                                 out + (size_t)BATCH * LSEQ * DDIM);
}

// Round 3
// 442.738 us; speedup vs baseline: 2.5040x; 1.0614x over previous
//
#include <hip/hip_runtime.h>
#include <hip/hip_bf16.h>

#define BATCH 8
#define LSEQ 2048
#define DDIM 512

using f32x4 = __attribute__((ext_vector_type(4))) float;
using s16x8 = __attribute__((ext_vector_type(8))) short;

static __device__ __forceinline__ unsigned short f2b(float f) {
  __hip_bfloat16 h = __float2bfloat16(f);
  return __builtin_bit_cast(unsigned short, h);
}
static __device__ __forceinline__ float b2f(unsigned short u) {
  unsigned int v = ((unsigned int)u) << 16;
  return __builtin_bit_cast(float, v);
}

// async global->LDS, 16B per lane. LDS dest = wave-uniform base + lane*16.
static __device__ __forceinline__ void gld16(const unsigned short* g, unsigned short* l) {
  __builtin_amdgcn_global_load_lds(
      (__attribute__((address_space(1))) void*)(g),
      (__attribute__((address_space(3))) void*)(l), 16, 0, 0);
}

// 128x128-tile bf16 MFMA K-loop, m97-style async staging, LP=32 (unpadded, required
// by global_load_lds contiguity). A row-major (m,k) lda; Bt row-major (n,k) ldb.
// 256 threads = 4 waves, each wave owns 64x64 (4x4 frags of 16x16x32).
__device__ __forceinline__ void mfma_kloop(
    const unsigned short* __restrict__ A, const unsigned short* __restrict__ Bt,
    int K, int lda, int ldb, unsigned short* sA, unsigned short* sB,
    int tid, f32x4 acc[4][4]) {
  const int wave = tid >> 6, lane = tid & 63;
  const int wm = (wave >> 1) * 64, wn = (wave & 1) * 64;
  const int lr = lane & 15, lq = lane >> 4;
  const int srow = tid >> 2;       // 0..63
  const int sk = (tid & 3) * 8;    // 0,8,16,24
  unsigned short* dA0 = sA + wave * 512;          // + implicit lane*8
  unsigned short* dA1 = sA + 2048 + wave * 512;
  unsigned short* dB0 = sB + wave * 512;
  unsigned short* dB1 = sB + 2048 + wave * 512;
  const unsigned short* pa0 = A + (size_t)srow * lda + sk;
  const unsigned short* pa1 = A + (size_t)(srow + 64) * lda + sk;
  const unsigned short* pb0 = Bt + (size_t)srow * ldb + sk;
  const unsigned short* pb1 = Bt + (size_t)(srow + 64) * ldb + sk;
  for (int k0 = 0; k0 < K; k0 += 32) {
    gld16(pa0 + k0, dA0);
    gld16(pa1 + k0, dA1);
    gld16(pb0 + k0, dB0);
    gld16(pb1 + k0, dB1);
    __syncthreads();
    s16x8 af[4], bf[4];
#pragma unroll
    for (int r = 0; r < 4; ++r)
      af[r] = *(const s16x8*)(sA + (wm + r * 16 + lr) * 32 + lq * 8);
#pragma unroll
    for (int c = 0; c < 4; ++c)
      bf[c] = *(const s16x8*)(sB + (wn + c * 16 + lr) * 32 + lq * 8);
#pragma unroll
    for (int r = 0; r < 4; ++r)
#pragma unroll
      for (int c = 0; c < 4; ++c)
        acc[r][c] = __builtin_amdgcn_mfma_f32_16x16x32_bf16(af[r], bf[c], acc[r][c], 0, 0, 0);
    __syncthreads();
  }
}

__global__ __launch_bounds__(256) void k_f2b(const float* __restrict__ in,
                                             unsigned short* __restrict__ out) {
  int idx = blockIdx.x * 256 + threadIdx.x;
  float4 v = ((const float4*)in)[idx];
  ushort4 o;
  o.x = f2b(v.x); o.y = f2b(v.y); o.z = f2b(v.z); o.w = f2b(v.w);
  ((ushort4*)out)[idx] = o;
}

__global__ __launch_bounds__(256) void k_transposeW(const float* __restrict__ W,
                                                    unsigned short* __restrict__ WT) {
  int idx = blockIdx.x * 256 + threadIdx.x;  // h*512 + d
  int h = idx >> 9, d = idx & 511;
  WT[idx] = f2b(W[d * DDIM + h]);
}

__global__ __launch_bounds__(256) void k_maskedmean_p1(const float* __restrict__ in,
                                                       const int* __restrict__ mask,
                                                       float* __restrict__ partial) {
  int b = blockIdx.y;
  int l0 = blockIdx.x * 32;
  __shared__ int sm[32];
  if (threadIdx.x < 32) sm[threadIdx.x] = mask[b * LSEQ + l0 + threadIdx.x];
  __syncthreads();
  int d = threadIdx.x * 2;
  const float* base = in + ((size_t)b * LSEQ + l0) * DDIM + d;
  float ax = 0.f, ay = 0.f;
#pragma unroll 4
  for (int r = 0; r < 32; ++r) {
    if (sm[r] == 0) {
      float2 v = *(const float2*)(base + (size_t)r * DDIM);
      ax += v.x; ay += v.y;
    }
  }
  float2 o; o.x = ax; o.y = ay;
  *(float2*)(partial + ((size_t)(b * 64 + blockIdx.x)) * DDIM + d) = o;
}

__global__ __launch_bounds__(256) void k_maskedmean_p2(const float* __restrict__ partial,
                                                       float* __restrict__ C) {
  int b = blockIdx.x;
  int d = threadIdx.x * 2;
  float ax = 0.f, ay = 0.f;
  for (int c = 0; c < 64; ++c) {
    float2 v = *(const float2*)(partial + ((size_t)(b * 64 + c)) * DDIM + d);
    ax += v.x; ay += v.y;
  }
  C[b * DDIM + d] = ax * (1.0f / LSEQ);
  C[b * DDIM + d + 1] = ay * (1.0f / LSEQ);
}

__global__ __launch_bounds__(256) void k_gemm_bias(const unsigned short* __restrict__ A,
                                                   const unsigned short* __restrict__ Bt,
                                                   const float* __restrict__ bias,
                                                   unsigned short* __restrict__ Cout) {
  __shared__ __align__(16) unsigned short sA[128 * 32], sB[128 * 32];
  f32x4 acc[4][4];
  f32x4 zero = {0.f, 0.f, 0.f, 0.f};
#pragma unroll
  for (int r = 0; r < 4; ++r)
#pragma unroll
    for (int c = 0; c < 4; ++c) acc[r][c] = zero;
  int bm = blockIdx.y * 128, bn = blockIdx.x * 128;
  mfma_kloop(A + (size_t)bm * DDIM, Bt + (size_t)bn * DDIM, DDIM, DDIM, DDIM,
             sA, sB, threadIdx.x, acc);
  int wave = threadIdx.x >> 6, lane = threadIdx.x & 63;
  int wm = (wave >> 1) * 64, wn = (wave & 1) * 64, lr = lane & 15, lq = lane >> 4;
#pragma unroll
  for (int r = 0; r < 4; ++r)
#pragma unroll
    for (int c = 0; c < 4; ++c)
#pragma unroll
      for (int rr = 0; rr < 4; ++rr) {
        int row = bm + wm + r * 16 + lq * 4 + rr;
        int col = bn + wn + c * 16 + lr;
        Cout[(size_t)row * DDIM + col] = f2b(acc[r][c][rr] + bias[col]);
      }
}

// E = mask ? exp(scale*mapa.mapb^T) : 0 (bf16, coalesced via LDS);
// fused row-sums (Zrow) and col-sums (Zcol) via atomics.
__global__ __launch_bounds__(256) void k_scores(const unsigned short* __restrict__ mapa,
                                                const unsigned short* __restrict__ mapb,
                                                const int* __restrict__ mask_a,
                                                const int* __restrict__ mask_b,
                                                unsigned short* __restrict__ E,
                                                float* __restrict__ Zrow,
                                                float* __restrict__ Zcol) {
  __shared__ __align__(16) unsigned short sA[128 * 32], sB[128 * 32];
  __shared__ __align__(16) unsigned short sT[128 * 136];  // [i][j], 16B-aligned rows
  __shared__ int sMa[128], sMb[128];
  int b = blockIdx.z;
  int bi = blockIdx.y * 128, bj = blockIdx.x * 128;
  int tid = threadIdx.x;
  if (tid < 128)
    sMa[tid] = mask_a[b * LSEQ + bi + tid];
  else
    sMb[tid - 128] = mask_b[b * LSEQ + bj + tid - 128];
  f32x4 acc[4][4];
  f32x4 zero = {0.f, 0.f, 0.f, 0.f};
#pragma unroll
  for (int r = 0; r < 4; ++r)
#pragma unroll
    for (int c = 0; c < 4; ++c) acc[r][c] = zero;
  mfma_kloop(mapa + ((size_t)b * LSEQ + bi) * DDIM, mapb + ((size_t)b * LSEQ + bj) * DDIM,
             DDIM, DDIM, DDIM, sA, sB, tid, acc);
  const float scale = 0.044194173824159216f;  // 1/sqrt(512)
  int wave = tid >> 6, lane = tid & 63;
  int wm = (wave >> 1) * 64, wn = (wave & 1) * 64, lr = lane & 15, lq = lane >> 4;
  float cs[4] = {0.f, 0.f, 0.f, 0.f};
#pragma unroll
  for (int r = 0; r < 4; ++r)
#pragma unroll
    for (int c = 0; c < 4; ++c)
#pragma unroll
      for (int rr = 0; rr < 4; ++rr) {
        int il = wm + r * 16 + lq * 4 + rr;
        int jl = wn + c * 16 + lr;
        float e = (sMa[il] && sMb[jl]) ? __expf(acc[r][c][rr] * scale) : 0.f;
        cs[c] += e;
        sT[il * 136 + jl] = f2b(e);
      }
  // column sums: reduce over lq (lanes ^16, ^32), then one atomic per column
#pragma unroll
  for (int c = 0; c < 4; ++c) {
    cs[c] += __shfl_xor(cs[c], 16);
    cs[c] += __shfl_xor(cs[c], 32);
  }
  if (lq == 0) {
#pragma unroll
    for (int c = 0; c < 4; ++c)
      atomicAdd(&Zcol[b * LSEQ + bj + wn + c * 16 + lr], cs[c]);
  }
  __syncthreads();
  // coalesced E store + fused row-sum
  unsigned short* Eb = E + (size_t)b * LSEQ * LSEQ;
  int i = tid >> 1, cb = (tid & 1) * 64;
  float rs = 0.f;
#pragma unroll
  for (int p = 0; p < 8; ++p) {
    uint4 v = *(const uint4*)(sT + i * 136 + cb + p * 8);
    *(uint4*)(Eb + (size_t)(bi + i) * LSEQ + bj + cb + p * 8) = v;
    unsigned int w[4] = {v.x, v.y, v.z, v.w};
#pragma unroll
    for (int q = 0; q < 4; ++q) {
      rs += b2f((unsigned short)(w[q] & 0xffffu));
      rs += b2f((unsigned short)(w[q] >> 16));
    }
  }
  atomicAdd(&Zrow[b * LSEQ + bi + i], rs);
}

// out[b,d,i] = (Z[b,i]>0 ? 1/Z[b,i] : 0) * in[b,i,d], bf16, transposed store.
__global__ __launch_bounds__(256) void k_scaleT(const float* __restrict__ in,
                                                const float* __restrict__ Z,
                                                unsigned short* __restrict__ out) {
  int b = blockIdx.z;
  int i0 = blockIdx.y * 64, d0 = blockIdx.x * 64;
  __shared__ unsigned short lt[64 * 65];
  __shared__ float zinv[64];
  if (threadIdx.x < 64) {
    float z = Z[b * LSEQ + i0 + threadIdx.x];
    zinv[threadIdx.x] = (z > 0.f) ? 1.f / z : 0.f;
  }
  __syncthreads();
  const float* ib = in + ((size_t)b * LSEQ + i0) * DDIM + d0;
#pragma unroll
  for (int p = 0; p < 16; ++p) {
    int idx = p * 256 + threadIdx.x;
    int dl = idx & 63, il = idx >> 6;
    lt[dl * 65 + il] = f2b(ib[(size_t)il * DDIM + dl] * zinv[il]);
  }
  __syncthreads();
  unsigned short* ob = out + ((size_t)b * DDIM + d0) * LSEQ + i0;
#pragma unroll
  for (int p = 0; p < 16; ++p) {
    int idx = p * 256 + threadIdx.x;
    int il = idx & 63, dl = idx >> 6;
    ob[(size_t)dl * LSEQ + il] = lt[dl * 65 + il];
  }
}

// output_a: Out[b,m,d] = (E @ btS^T)[m,d] + addin + Cvec. E k-contiguous (k=j).
__global__ __launch_bounds__(256) void k_gemm_out(const unsigned short* __restrict__ Eop,
                                                  const unsigned short* __restrict__ Sop,
                                                  const float* __restrict__ addin,
                                                  const float* __restrict__ Cvec,
                                                  float* __restrict__ Out) {
  __shared__ __align__(16) unsigned short sA[128 * 32], sB[128 * 32];
  int b = blockIdx.z;
  int bm = blockIdx.y * 128, bn = blockIdx.x * 128;
  f32x4 acc[4][4];
  f32x4 zero = {0.f, 0.f, 0.f, 0.f};
#pragma unroll
  for (int r = 0; r < 4; ++r)
#pragma unroll
    for (int c = 0; c < 4; ++c) acc[r][c] = zero;
  mfma_kloop(Eop + (size_t)b * LSEQ * LSEQ + (size_t)bm * LSEQ,
             Sop + (size_t)b * DDIM * LSEQ + (size_t)bn * LSEQ,
             LSEQ, LSEQ, LSEQ, sA, sB, threadIdx.x, acc);
  int wave = threadIdx.x >> 6, lane = threadIdx.x & 63;
  int wm = (wave >> 1) * 64, wn = (wave & 1) * 64, lr = lane & 15, lq = lane >> 4;
#pragma unroll
  for (int r = 0; r < 4; ++r)
#pragma unroll
    for (int c = 0; c < 4; ++c)
#pragma unroll
      for (int rr = 0; rr < 4; ++rr) {
        int row = bm + wm + r * 16 + lq * 4 + rr;
        int col = bn + wn + c * 16 + lr;
        size_t o = ((size_t)b * LSEQ + row) * DDIM + col;
        Out[o] = acc[r][c][rr] + addin[o] + Cvec[b * DDIM + col];
      }
}

// output_b: A = E^T staged via in-kernel transpose (A[m=j][k=i] = E[i][j]).
__global__ __launch_bounds__(256) void k_gemm_outT(const unsigned short* __restrict__ E,
                                                   const unsigned short* __restrict__ Sop,
                                                   const float* __restrict__ addin,
                                                   const float* __restrict__ Cvec,
                                                   float* __restrict__ Out) {
  __shared__ __align__(16) unsigned short sA[128 * 32], sB[128 * 32];
  int b = blockIdx.z;
  int bm = blockIdx.y * 128, bn = blockIdx.x * 128;  // bm over Lb(j), bn over D
  int tid = threadIdx.x;
  const int wave = tid >> 6, lane = tid & 63;
  const int wm = (wave >> 1) * 64, wn = (wave & 1) * 64;
  const int lr = lane & 15, lq = lane >> 4;
  const int srow = tid >> 2, sk = (tid & 3) * 8;
  f32x4 acc[4][4];
  f32x4 zero = {0.f, 0.f, 0.f, 0.f};
#pragma unroll
  for (int r = 0; r < 4; ++r)
#pragma unroll
    for (int c = 0; c < 4; ++c) acc[r][c] = zero;
  unsigned short* dB0 = sB + wave * 512;
  unsigned short* dB1 = sB + 2048 + wave * 512;
  const unsigned short* Bb = Sop + (size_t)b * DDIM * LSEQ + (size_t)bn * LSEQ;
  const unsigned short* pb0 = Bb + (size_t)srow * LSEQ + sk;
  const unsigned short* pb1 = Bb + (size_t)(srow + 64) * LSEQ + sk;
  const int tk = (tid & 15) * 2;   // k-pair within 32-tile
  const int tm = (tid >> 4) * 8;   // m-chunk (j-cols of E)
  const unsigned short* pe = E + (size_t)b * LSEQ * LSEQ + (size_t)tk * LSEQ + bm + tm;
  for (int k0 = 0; k0 < LSEQ; k0 += 32) {
    gld16(pb0 + k0, dB0);
    gld16(pb1 + k0, dB1);
    uint4 e0 = *(const uint4*)(pe + (size_t)k0 * LSEQ);
    uint4 e1 = *(const uint4*)(pe + (size_t)k0 * LSEQ + LSEQ);
    unsigned short t0[8], t1[8];
    *(uint4*)t0 = e0; *(uint4*)t1 = e1;
#pragma unroll
    for (int j = 0; j < 8; ++j) {
      unsigned int v = (unsigned int)t0[j] | ((unsigned int)t1[j] << 16);
      *(unsigned int*)(sA + (tm + j) * 32 + tk) = v;
    }
    __syncthreads();
    s16x8 af[4], bf[4];
#pragma unroll
    for (int r = 0; r < 4; ++r)
      af[r] = *(const s16x8*)(sA + (wm + r * 16 + lr) * 32 + lq * 8);
#pragma unroll
    for (int c = 0; c < 4; ++c)
      bf[c] = *(const s16x8*)(sB + (wn + c * 16 + lr) * 32 + lq * 8);
#pragma unroll
    for (int r = 0; r < 4; ++r)
#pragma unroll
      for (int c = 0; c < 4; ++c)
        acc[r][c] = __builtin_amdgcn_mfma_f32_16x16x32_bf16(af[r], bf[c], acc[r][c], 0, 0, 0);
    __syncthreads();
  }
#pragma unroll
  for (int r = 0; r < 4; ++r)
#pragma unroll
    for (int c = 0; c < 4; ++c)
#pragma unroll
      for (int rr = 0; rr < 4; ++rr) {
        int row = bm + wm + r * 16 + lq * 4 + rr;
        int col = bn + wn + c * 16 + lr;
        size_t o = ((size_t)b * LSEQ + row) * DDIM + col;
        Out[o] = acc[r][c][rr] + addin[o] + Cvec[b * DDIM + col];
      }
}

extern "C" void kernel_launch(void* const* d_in, const int* in_sizes, int n_in,
                              void* d_out, int out_size, void* d_ws, size_t ws_size,
                              hipStream_t stream) {
  (void)in_sizes; (void)n_in; (void)out_size; (void)ws_size;
  const float* in_a = (const float*)d_in[0];
  const float* in_b = (const float*)d_in[1];
  const int* ma = (const int*)d_in[2];
  const int* mb = (const int*)d_in[3];
  const float* Wa = (const float*)d_in[4];
  const float* ba = (const float*)d_in[5];
  const float* Wb = (const float*)d_in[6];
  const float* bb = (const float*)d_in[7];
  float* out = (float*)d_out;

  char* ws = (char*)d_ws;
  const size_t MB = 1ull << 20;
  unsigned short* a16 = (unsigned short*)(ws + 0 * MB);    // 16MB (reused as atS)
  unsigned short* b16 = (unsigned short*)(ws + 16 * MB);   // 16MB (reused as btS)
  unsigned short* WaT = (unsigned short*)(ws + 32 * MB);   // 0.5MB
  unsigned short* WbT = (unsigned short*)(ws + 32 * MB + 512 * 1024);
  unsigned short* mapa = (unsigned short*)(ws + 33 * MB);  // 16MB
  unsigned short* mapb = (unsigned short*)(ws + 49 * MB);  // 16MB
  unsigned short* E = (unsigned short*)(ws + 65 * MB);     // 64MB
  float* Zrow = (float*)(ws + 129 * MB);                   // 64KB
  float* Zcol = (float*)(ws + 129 * MB + 65536);           // 64KB
  float* Ca = (float*)(ws + 129 * MB + 2 * 65536);         // 16KB
  float* Cb = (float*)(ws + 129 * MB + 2 * 65536 + 16384); // 16KB
  float* Pmm = (float*)(ws + 129 * MB + 2 * 65536 + 2 * 16384);  // 1MB partials
  unsigned short* atS = a16;  // [B,512,2048] input_a/Zrow transposed
  unsigned short* btS = b16;  // [B,512,2048] input_b/Zcol transposed

  hipMemsetAsync(Zrow, 0, 2 * 65536, stream);  // Zrow + Zcol
  k_f2b<<<8192, 256, 0, stream>>>(in_a, a16);
  k_f2b<<<8192, 256, 0, stream>>>(in_b, b16);
  k_transposeW<<<1024, 256, 0, stream>>>(Wa, WaT);
  k_transposeW<<<1024, 256, 0, stream>>>(Wb, WbT);
  k_maskedmean_p1<<<dim3(64, 8), 256, 0, stream>>>(in_a, ma, Pmm);
  k_maskedmean_p2<<<8, 256, 0, stream>>>(Pmm, Ca);
  k_maskedmean_p1<<<dim3(64, 8), 256, 0, stream>>>(in_b, mb, Pmm);
  k_maskedmean_p2<<<8, 256, 0, stream>>>(Pmm, Cb);
  k_gemm_bias<<<dim3(4, 128), 256, 0, stream>>>(a16, WaT, ba, mapa);
  k_gemm_bias<<<dim3(4, 128), 256, 0, stream>>>(b16, WbT, bb, mapb);
  k_scores<<<dim3(16, 16, 8), 256, 0, stream>>>(mapa, mapb, ma, mb, E, Zrow, Zcol);
  k_scaleT<<<dim3(8, 32, 8), 256, 0, stream>>>(in_a, Zrow, atS);
  k_scaleT<<<dim3(8, 32, 8), 256, 0, stream>>>(in_b, Zcol, btS);
  k_gemm_out<<<dim3(4, 16, 8), 256, 0, stream>>>(E, btS, in_a, Cb, out);
  k_gemm_outT<<<dim3(4, 16, 8), 256, 0, stream>>>(E, atS, in_b, Ca,
                                                  out + (size_t)BATCH * LSEQ * DDIM);
}

// Round 4
// 382.578 us; speedup vs baseline: 2.8977x; 1.1572x over previous
//
#include <hip/hip_runtime.h>
#include <hip/hip_bf16.h>

#define BATCH 8
#define LSEQ 2048
#define DDIM 512

using f32x4 = __attribute__((ext_vector_type(4))) float;
using s16x8 = __attribute__((ext_vector_type(8))) short;

static __device__ __forceinline__ unsigned short f2b(float f) {
  __hip_bfloat16 h = __float2bfloat16(f);
  return __builtin_bit_cast(unsigned short, h);
}
static __device__ __forceinline__ float b2f(unsigned short u) {
  unsigned int v = ((unsigned int)u) << 16;
  return __builtin_bit_cast(float, v);
}

// async global->LDS, 16B per lane. LDS dest = wave-uniform base + lane*16.
static __device__ __forceinline__ void gld16(const unsigned short* g, unsigned short* l) {
  __builtin_amdgcn_global_load_lds(
      (__attribute__((address_space(1))) void*)(g),
      (__attribute__((address_space(3))) void*)(l), 16, 0, 0);
}

// 128x128-tile bf16 MFMA K-loop, m97-style async staging, row stride 32 (unpadded,
// required by global_load_lds contiguity). 256 threads = 4 waves, 64x64/wave.
__device__ __forceinline__ void mfma_kloop(
    const unsigned short* __restrict__ A, const unsigned short* __restrict__ Bt,
    int K, int lda, int ldb, unsigned short* sA, unsigned short* sB,
    int tid, f32x4 acc[4][4]) {
  const int wave = tid >> 6, lane = tid & 63;
  const int wm = (wave >> 1) * 64, wn = (wave & 1) * 64;
  const int lr = lane & 15, lq = lane >> 4;
  const int srow = tid >> 2;       // 0..63
  const int sk = (tid & 3) * 8;    // 0,8,16,24
  unsigned short* dA0 = sA + wave * 512;          // + implicit lane*8
  unsigned short* dA1 = sA + 2048 + wave * 512;
  unsigned short* dB0 = sB + wave * 512;
  unsigned short* dB1 = sB + 2048 + wave * 512;
  const unsigned short* pa0 = A + (size_t)srow * lda + sk;
  const unsigned short* pa1 = A + (size_t)(srow + 64) * lda + sk;
  const unsigned short* pb0 = Bt + (size_t)srow * ldb + sk;
  const unsigned short* pb1 = Bt + (size_t)(srow + 64) * ldb + sk;
  for (int k0 = 0; k0 < K; k0 += 32) {
    gld16(pa0 + k0, dA0);
    gld16(pa1 + k0, dA1);
    gld16(pb0 + k0, dB0);
    gld16(pb1 + k0, dB1);
    __syncthreads();
    s16x8 af[4], bf[4];
#pragma unroll
    for (int r = 0; r < 4; ++r)
      af[r] = *(const s16x8*)(sA + (wm + r * 16 + lr) * 32 + lq * 8);
#pragma unroll
    for (int c = 0; c < 4; ++c)
      bf[c] = *(const s16x8*)(sB + (wn + c * 16 + lr) * 32 + lq * 8);
#pragma unroll
    for (int r = 0; r < 4; ++r)
#pragma unroll
      for (int c = 0; c < 4; ++c)
        acc[r][c] = __builtin_amdgcn_mfma_f32_16x16x32_bf16(af[r], bf[c], acc[r][c], 0, 0, 0);
    __syncthreads();
  }
}

// Fused f32->bf16 convert + masked partial sum. z selects input a/b.
__global__ __launch_bounds__(256) void k_prep(const float* __restrict__ in_a,
                                              const float* __restrict__ in_b,
                                              const int* __restrict__ ma,
                                              const int* __restrict__ mb,
                                              unsigned short* __restrict__ oa,
                                              unsigned short* __restrict__ ob,
                                              float* __restrict__ Pa,
                                              float* __restrict__ Pb) {
  int z = blockIdx.z;
  const float* in = z ? in_b : in_a;
  const int* mask = z ? mb : ma;
  unsigned short* o16 = z ? ob : oa;
  float* partial = z ? Pb : Pa;
  int b = blockIdx.y;
  int l0 = blockIdx.x * 32;
  __shared__ int sm[32];
  if (threadIdx.x < 32) sm[threadIdx.x] = mask[b * LSEQ + l0 + threadIdx.x];
  __syncthreads();
  int d = threadIdx.x * 2;
  const float* base = in + ((size_t)b * LSEQ + l0) * DDIM + d;
  unsigned short* obase = o16 + ((size_t)b * LSEQ + l0) * DDIM + d;
  float ax = 0.f, ay = 0.f;
#pragma unroll 4
  for (int r = 0; r < 32; ++r) {
    float2 v = *(const float2*)(base + (size_t)r * DDIM);
    ushort2 u; u.x = f2b(v.x); u.y = f2b(v.y);
    *(ushort2*)(obase + (size_t)r * DDIM) = u;
    if (sm[r] == 0) { ax += v.x; ay += v.y; }
  }
  float2 o; o.x = ax; o.y = ay;
  *(float2*)(partial + ((size_t)(b * 64 + blockIdx.x)) * DDIM + d) = o;
}

// Stage 2 for both inputs: C[b,d] = (1/L)*sum partials. grid 16.
__global__ __launch_bounds__(256) void k_p2(const float* __restrict__ Pa,
                                            const float* __restrict__ Pb,
                                            float* __restrict__ Ca,
                                            float* __restrict__ Cb) {
  int g = blockIdx.x;
  const float* src = (g < 8) ? Pa : Pb;
  float* dst = (g < 8) ? Ca : Cb;
  int b = g & 7;
  int d = threadIdx.x * 2;
  float ax = 0.f, ay = 0.f;
  for (int c = 0; c < 64; ++c) {
    float2 v = *(const float2*)(src + ((size_t)(b * 64 + c)) * DDIM + d);
    ax += v.x; ay += v.y;
  }
  dst[b * DDIM + d] = ax * (1.0f / LSEQ);
  dst[b * DDIM + d + 1] = ay * (1.0f / LSEQ);
}

// Both weights [D,H] f32 -> [H,D] bf16. grid 2048 covers 2x512x512.
__global__ __launch_bounds__(256) void k_transposeW(const float* __restrict__ Wa,
                                                    const float* __restrict__ Wb,
                                                    unsigned short* __restrict__ WaT,
                                                    unsigned short* __restrict__ WbT) {
  int gidx = blockIdx.x * 256 + threadIdx.x;
  const float* W = (gidx < 512 * 512) ? Wa : Wb;
  unsigned short* WT = (gidx < 512 * 512) ? WaT : WbT;
  int idx = gidx & (512 * 512 - 1);
  int h = idx >> 9, d = idx & 511;
  WT[idx] = f2b(W[d * DDIM + h]);
}

// mapped = A(bf16) @ W^T(bf16) + bias -> bf16. z selects a/b.
__global__ __launch_bounds__(256) void k_gemm_bias(const unsigned short* __restrict__ a16,
                                                   const unsigned short* __restrict__ b16,
                                                   const unsigned short* __restrict__ WaT,
                                                   const unsigned short* __restrict__ WbT,
                                                   const float* __restrict__ ba,
                                                   const float* __restrict__ bb,
                                                   unsigned short* __restrict__ mapa,
                                                   unsigned short* __restrict__ mapb) {
  int z = blockIdx.z;
  const unsigned short* A = z ? b16 : a16;
  const unsigned short* Bt = z ? WbT : WaT;
  const float* bias = z ? bb : ba;
  unsigned short* Cout = z ? mapb : mapa;
  __shared__ __align__(16) unsigned short sA[128 * 32], sB[128 * 32];
  f32x4 acc[4][4];
  f32x4 zero = {0.f, 0.f, 0.f, 0.f};
#pragma unroll
  for (int r = 0; r < 4; ++r)
#pragma unroll
    for (int c = 0; c < 4; ++c) acc[r][c] = zero;
  int bm = blockIdx.y * 128, bn = blockIdx.x * 128;
  mfma_kloop(A + (size_t)bm * DDIM, Bt + (size_t)bn * DDIM, DDIM, DDIM, DDIM,
             sA, sB, threadIdx.x, acc);
  int wave = threadIdx.x >> 6, lane = threadIdx.x & 63;
  int wm = (wave >> 1) * 64, wn = (wave & 1) * 64, lr = lane & 15, lq = lane >> 4;
#pragma unroll
  for (int r = 0; r < 4; ++r)
#pragma unroll
    for (int c = 0; c < 4; ++c)
#pragma unroll
      for (int rr = 0; rr < 4; ++rr) {
        int row = bm + wm + r * 16 + lq * 4 + rr;
        int col = bn + wn + c * 16 + lr;
        Cout[(size_t)row * DDIM + col] = f2b(acc[r][c][rr] + bias[col]);
      }
}

// E = mask ? exp(scale*mapa.mapb^T) : 0, stored directly from C-layout (bf16);
// fused row/col sums via shfl butterflies + global atomics. LDS = 17 KB only.
__global__ __launch_bounds__(256) void k_scores(const unsigned short* __restrict__ mapa,
                                                const unsigned short* __restrict__ mapb,
                                                const int* __restrict__ mask_a,
                                                const int* __restrict__ mask_b,
                                                unsigned short* __restrict__ E,
                                                float* __restrict__ Zrow,
                                                float* __restrict__ Zcol) {
  __shared__ __align__(16) unsigned short sA[128 * 32], sB[128 * 32];
  __shared__ int sMa[128], sMb[128];
  int b = blockIdx.z;
  int bi = blockIdx.y * 128, bj = blockIdx.x * 128;
  int tid = threadIdx.x;
  if (tid < 128)
    sMa[tid] = mask_a[b * LSEQ + bi + tid];
  else
    sMb[tid - 128] = mask_b[b * LSEQ + bj + tid - 128];
  f32x4 acc[4][4];
  f32x4 zero = {0.f, 0.f, 0.f, 0.f};
#pragma unroll
  for (int r = 0; r < 4; ++r)
#pragma unroll
    for (int c = 0; c < 4; ++c) acc[r][c] = zero;
  mfma_kloop(mapa + ((size_t)b * LSEQ + bi) * DDIM, mapb + ((size_t)b * LSEQ + bj) * DDIM,
             DDIM, DDIM, DDIM, sA, sB, tid, acc);
  const float scale = 0.044194173824159216f;  // 1/sqrt(512)
  int wave = tid >> 6, lane = tid & 63;
  int wm = (wave >> 1) * 64, wn = (wave & 1) * 64, lr = lane & 15, lq = lane >> 4;
  unsigned short* Eb = E + (size_t)b * LSEQ * LSEQ + (size_t)bi * LSEQ + bj;
  float colp[4] = {0.f, 0.f, 0.f, 0.f};
  float rowp[4][4];
#pragma unroll
  for (int r = 0; r < 4; ++r) {
#pragma unroll
    for (int rr = 0; rr < 4; ++rr) rowp[r][rr] = 0.f;
#pragma unroll
    for (int c = 0; c < 4; ++c) {
      int jl = wn + c * 16 + lr;
      int mb_ = sMb[jl];
#pragma unroll
      for (int rr = 0; rr < 4; ++rr) {
        int il = wm + r * 16 + lq * 4 + rr;
        float e = (sMa[il] && mb_) ? __expf(acc[r][c][rr] * scale) : 0.f;
        rowp[r][rr] += e;
        colp[c] += e;
        Eb[(size_t)il * LSEQ + jl] = f2b(e);
      }
    }
  }
  // row sums: butterfly over lr (xor 1,2,4,8), one atomic per row (lr==0 lanes)
#pragma unroll
  for (int r = 0; r < 4; ++r)
#pragma unroll
    for (int rr = 0; rr < 4; ++rr) {
      float v = rowp[r][rr];
      v += __shfl_xor(v, 1);
      v += __shfl_xor(v, 2);
      v += __shfl_xor(v, 4);
      v += __shfl_xor(v, 8);
      if (lr == 0) {
        int il = wm + r * 16 + lq * 4 + rr;
        atomicAdd(&Zrow[b * LSEQ + bi + il], v);
      }
    }
  // col sums: butterfly over lq (xor 16,32), one atomic per col (lq==0 lanes)
#pragma unroll
  for (int c = 0; c < 4; ++c) {
    float v = colp[c];
    v += __shfl_xor(v, 16);
    v += __shfl_xor(v, 32);
    if (lq == 0) atomicAdd(&Zcol[b * LSEQ + bj + wn + c * 16 + lr], v);
  }
}

// out[b,d,i] = (Z[b,i]>0 ? 1/Z[b,i] : 0) * in16[b,i,d], transposed store.
// z = blockIdx.z: low 3 bits batch, bit 3 selects (a,Zrow,atS) vs (b,Zcol,btS).
__global__ __launch_bounds__(256) void k_scaleT(const unsigned short* __restrict__ a16,
                                                const unsigned short* __restrict__ b16,
                                                const float* __restrict__ Zrow,
                                                const float* __restrict__ Zcol,
                                                unsigned short* __restrict__ atS,
                                                unsigned short* __restrict__ btS) {
  int zz = blockIdx.z;
  int b = zz & 7, sel = zz >> 3;
  const unsigned short* in = sel ? b16 : a16;
  const float* Z = sel ? Zcol : Zrow;
  unsigned short* out = sel ? btS : atS;
  int i0 = blockIdx.y * 64, d0 = blockIdx.x * 64;
  __shared__ unsigned short lt[64 * 65];
  __shared__ float zinv[64];
  if (threadIdx.x < 64) {
    float z = Z[b * LSEQ + i0 + threadIdx.x];
    zinv[threadIdx.x] = (z > 0.f) ? 1.f / z : 0.f;
  }
  __syncthreads();
  const unsigned short* ib = in + ((size_t)b * LSEQ + i0) * DDIM + d0;
#pragma unroll
  for (int p = 0; p < 16; ++p) {
    int idx = p * 256 + threadIdx.x;
    int dl = idx & 63, il = idx >> 6;
    lt[dl * 65 + il] = f2b(b2f(ib[(size_t)il * DDIM + dl]) * zinv[il]);
  }
  __syncthreads();
  unsigned short* ob = out + ((size_t)b * DDIM + d0) * LSEQ + i0;
#pragma unroll
  for (int p = 0; p < 16; ++p) {
    int idx = p * 256 + threadIdx.x;
    int il = idx & 63, dl = idx >> 6;
    ob[(size_t)dl * LSEQ + il] = lt[dl * 65 + il];
  }
}

// output_a: Out[b,m,d] = (E @ btS^T)[m,d] + addin + Cvec. E k-contiguous (k=j).
__global__ __launch_bounds__(256) void k_gemm_out(const unsigned short* __restrict__ Eop,
                                                  const unsigned short* __restrict__ Sop,
                                                  const float* __restrict__ addin,
                                                  const float* __restrict__ Cvec,
                                                  float* __restrict__ Out) {
  __shared__ __align__(16) unsigned short sA[128 * 32], sB[128 * 32];
  int b = blockIdx.z;
  int bm = blockIdx.y * 128, bn = blockIdx.x * 128;
  f32x4 acc[4][4];
  f32x4 zero = {0.f, 0.f, 0.f, 0.f};
#pragma unroll
  for (int r = 0; r < 4; ++r)
#pragma unroll
    for (int c = 0; c < 4; ++c) acc[r][c] = zero;
  mfma_kloop(Eop + (size_t)b * LSEQ * LSEQ + (size_t)bm * LSEQ,
             Sop + (size_t)b * DDIM * LSEQ + (size_t)bn * LSEQ,
             LSEQ, LSEQ, LSEQ, sA, sB, threadIdx.x, acc);
  int wave = threadIdx.x >> 6, lane = threadIdx.x & 63;
  int wm = (wave >> 1) * 64, wn = (wave & 1) * 64, lr = lane & 15, lq = lane >> 4;
#pragma unroll
  for (int r = 0; r < 4; ++r)
#pragma unroll
    for (int c = 0; c < 4; ++c)
#pragma unroll
      for (int rr = 0; rr < 4; ++rr) {
        int row = bm + wm + r * 16 + lq * 4 + rr;
        int col = bn + wn + c * 16 + lr;
        size_t o = ((size_t)b * LSEQ + row) * DDIM + col;
        Out[o] = acc[r][c][rr] + addin[o] + Cvec[b * DDIM + col];
      }
}

// output_b: A = E^T staged via in-kernel transpose (A[m=j][k=i] = E[i][j]).
__global__ __launch_bounds__(256) void k_gemm_outT(const unsigned short* __restrict__ E,
                                                   const unsigned short* __restrict__ Sop,
                                                   const float* __restrict__ addin,
                                                   const float* __restrict__ Cvec,
                                                   float* __restrict__ Out) {
  __shared__ __align__(16) unsigned short sA[128 * 32], sB[128 * 32];
  int b = blockIdx.z;
  int bm = blockIdx.y * 128, bn = blockIdx.x * 128;  // bm over Lb(j), bn over D
  int tid = threadIdx.x;
  const int wave = tid >> 6, lane = tid & 63;
  const int wm = (wave >> 1) * 64, wn = (wave & 1) * 64;
  const int lr = lane & 15, lq = lane >> 4;
  const int srow = tid >> 2, sk = (tid & 3) * 8;
  f32x4 acc[4][4];
  f32x4 zero = {0.f, 0.f, 0.f, 0.f};
#pragma unroll
  for (int r = 0; r < 4; ++r)
#pragma unroll
    for (int c = 0; c < 4; ++c) acc[r][c] = zero;
  unsigned short* dB0 = sB + wave * 512;
  unsigned short* dB1 = sB + 2048 + wave * 512;
  const unsigned short* Bb = Sop + (size_t)b * DDIM * LSEQ + (size_t)bn * LSEQ;
  const unsigned short* pb0 = Bb + (size_t)srow * LSEQ + sk;
  const unsigned short* pb1 = Bb + (size_t)(srow + 64) * LSEQ + sk;
  const int tk = (tid & 15) * 2;   // k-pair within 32-tile
  const int tm = (tid >> 4) * 8;   // m-chunk (j-cols of E)
  const unsigned short* pe = E + (size_t)b * LSEQ * LSEQ + (size_t)tk * LSEQ + bm + tm;
  for (int k0 = 0; k0 < LSEQ; k0 += 32) {
    gld16(pb0 + k0, dB0);
    gld16(pb1 + k0, dB1);
    uint4 e0 = *(const uint4*)(pe + (size_t)k0 * LSEQ);
    uint4 e1 = *(const uint4*)(pe + (size_t)k0 * LSEQ + LSEQ);
    unsigned short t0[8], t1[8];
    *(uint4*)t0 = e0; *(uint4*)t1 = e1;
#pragma unroll
    for (int j = 0; j < 8; ++j) {
      unsigned int v = (unsigned int)t0[j] | ((unsigned int)t1[j] << 16);
      *(unsigned int*)(sA + (tm + j) * 32 + tk) = v;
    }
    __syncthreads();
    s16x8 af[4], bf[4];
#pragma unroll
    for (int r = 0; r < 4; ++r)
      af[r] = *(const s16x8*)(sA + (wm + r * 16 + lr) * 32 + lq * 8);
#pragma unroll
    for (int c = 0; c < 4; ++c)
      bf[c] = *(const s16x8*)(sB + (wn + c * 16 + lr) * 32 + lq * 8);
#pragma unroll
    for (int r = 0; r < 4; ++r)
#pragma unroll
      for (int c = 0; c < 4; ++c)
        acc[r][c] = __builtin_amdgcn_mfma_f32_16x16x32_bf16(af[r], bf[c], acc[r][c], 0, 0, 0);
    __syncthreads();
  }
#pragma unroll
  for (int r = 0; r < 4; ++r)
#pragma unroll
    for (int c = 0; c < 4; ++c)
#pragma unroll
      for (int rr = 0; rr < 4; ++rr) {
        int row = bm + wm + r * 16 + lq * 4 + rr;
        int col = bn + wn + c * 16 + lr;
        size_t o = ((size_t)b * LSEQ + row) * DDIM + col;
        Out[o] = acc[r][c][rr] + addin[o] + Cvec[b * DDIM + col];
      }
}

extern "C" void kernel_launch(void* const* d_in, const int* in_sizes, int n_in,
                              void* d_out, int out_size, void* d_ws, size_t ws_size,
                              hipStream_t stream) {
  (void)in_sizes; (void)n_in; (void)out_size; (void)ws_size;
  const float* in_a = (const float*)d_in[0];
  const float* in_b = (const float*)d_in[1];
  const int* ma = (const int*)d_in[2];
  const int* mb = (const int*)d_in[3];
  const float* Wa = (const float*)d_in[4];
  const float* ba = (const float*)d_in[5];
  const float* Wb = (const float*)d_in[6];
  const float* bb = (const float*)d_in[7];
  float* out = (float*)d_out;

  char* ws = (char*)d_ws;
  const size_t MB = 1ull << 20;
  unsigned short* a16 = (unsigned short*)(ws + 0 * MB);    // 16MB
  unsigned short* b16 = (unsigned short*)(ws + 16 * MB);   // 16MB
  unsigned short* WaT = (unsigned short*)(ws + 32 * MB);   // 0.5MB
  unsigned short* WbT = (unsigned short*)(ws + 32 * MB + 512 * 1024);
  unsigned short* mapa = (unsigned short*)(ws + 33 * MB);  // 16MB
  unsigned short* mapb = (unsigned short*)(ws + 49 * MB);  // 16MB
  unsigned short* E = (unsigned short*)(ws + 65 * MB);     // 64MB
  unsigned short* atS = (unsigned short*)(ws + 129 * MB);  // 16MB
  unsigned short* btS = (unsigned short*)(ws + 145 * MB);  // 16MB
  float* Zrow = (float*)(ws + 161 * MB);                   // 64KB
  float* Zcol = (float*)(ws + 161 * MB + 65536);           // 64KB
  float* Ca = (float*)(ws + 161 * MB + 2 * 65536);         // 16KB
  float* Cb = (float*)(ws + 161 * MB + 2 * 65536 + 16384); // 16KB
  float* Pa = (float*)(ws + 162 * MB);                     // 1MB
  float* Pb = (float*)(ws + 163 * MB);                     // 1MB

  hipMemsetAsync(Zrow, 0, 2 * 65536, stream);  // Zrow + Zcol
  k_prep<<<dim3(64, 8, 2), 256, 0, stream>>>(in_a, in_b, ma, mb, a16, b16, Pa, Pb);
  k_transposeW<<<2048, 256, 0, stream>>>(Wa, Wb, WaT, WbT);
  k_p2<<<16, 256, 0, stream>>>(Pa, Pb, Ca, Cb);
  k_gemm_bias<<<dim3(4, 128, 2), 256, 0, stream>>>(a16, b16, WaT, WbT, ba, bb, mapa, mapb);
  k_scores<<<dim3(16, 16, 8), 256, 0, stream>>>(mapa, mapb, ma, mb, E, Zrow, Zcol);
  k_scaleT<<<dim3(8, 32, 16), 256, 0, stream>>>(a16, b16, Zrow, Zcol, atS, btS);
  k_gemm_out<<<dim3(4, 16, 8), 256, 0, stream>>>(E, btS, in_a, Cb, out);
  k_gemm_outT<<<dim3(4, 16, 8), 256, 0, stream>>>(E, atS, in_b, Ca,
                                                  out + (size_t)BATCH * LSEQ * DDIM);
}

// Round 5
// 378.310 us; speedup vs baseline: 2.9304x; 1.0113x over previous
//
#include <hip/hip_runtime.h>
#include <hip/hip_bf16.h>

#define BATCH 8
#define LSEQ 2048
#define DDIM 512

using f32x4 = __attribute__((ext_vector_type(4))) float;
using s16x8 = __attribute__((ext_vector_type(8))) short;

static __device__ __forceinline__ unsigned short f2b(float f) {
  __hip_bfloat16 h = __float2bfloat16(f);
  return __builtin_bit_cast(unsigned short, h);
}
static __device__ __forceinline__ float b2f(unsigned short u) {
  unsigned int v = ((unsigned int)u) << 16;
  return __builtin_bit_cast(float, v);
}

// async global->LDS, 16B per lane. LDS dest = wave-uniform base + lane*16.
static __device__ __forceinline__ void gld16(const unsigned short* g, unsigned short* l) {
  __builtin_amdgcn_global_load_lds(
      (__attribute__((address_space(1))) void*)(g),
      (__attribute__((address_space(3))) void*)(l), 16, 0, 0);
}

// 128x128-tile bf16 MFMA K-loop, async staging, row stride 32 (unpadded, required
// by global_load_lds contiguity). 256 threads = 4 waves, 64x64/wave.
__device__ __forceinline__ void mfma_kloop(
    const unsigned short* __restrict__ A, const unsigned short* __restrict__ Bt,
    int K, int lda, int ldb, unsigned short* sA, unsigned short* sB,
    int tid, f32x4 acc[4][4]) {
  const int wave = tid >> 6, lane = tid & 63;
  const int wm = (wave >> 1) * 64, wn = (wave & 1) * 64;
  const int lr = lane & 15, lq = lane >> 4;
  const int srow = tid >> 2;       // 0..63
  const int sk = (tid & 3) * 8;    // 0,8,16,24
  unsigned short* dA0 = sA + wave * 512;          // + implicit lane*8
  unsigned short* dA1 = sA + 2048 + wave * 512;
  unsigned short* dB0 = sB + wave * 512;
  unsigned short* dB1 = sB + 2048 + wave * 512;
  const unsigned short* pa0 = A + (size_t)srow * lda + sk;
  const unsigned short* pa1 = A + (size_t)(srow + 64) * lda + sk;
  const unsigned short* pb0 = Bt + (size_t)srow * ldb + sk;
  const unsigned short* pb1 = Bt + (size_t)(srow + 64) * ldb + sk;
  for (int k0 = 0; k0 < K; k0 += 32) {
    gld16(pa0 + k0, dA0);
    gld16(pa1 + k0, dA1);
    gld16(pb0 + k0, dB0);
    gld16(pb1 + k0, dB1);
    __syncthreads();
    s16x8 af[4], bf[4];
#pragma unroll
    for (int r = 0; r < 4; ++r)
      af[r] = *(const s16x8*)(sA + (wm + r * 16 + lr) * 32 + lq * 8);
#pragma unroll
    for (int c = 0; c < 4; ++c)
      bf[c] = *(const s16x8*)(sB + (wn + c * 16 + lr) * 32 + lq * 8);
#pragma unroll
    for (int r = 0; r < 4; ++r)
#pragma unroll
      for (int c = 0; c < 4; ++c)
        acc[r][c] = __builtin_amdgcn_mfma_f32_16x16x32_bf16(af[r], bf[c], acc[r][c], 0, 0, 0);
    __syncthreads();
  }
}

// Fused f32->bf16 convert + masked partial sum. z selects input a/b.
__global__ __launch_bounds__(256) void k_prep(const float* __restrict__ in_a,
                                              const float* __restrict__ in_b,
                                              const int* __restrict__ ma,
                                              const int* __restrict__ mb,
                                              unsigned short* __restrict__ oa,
                                              unsigned short* __restrict__ ob,
                                              float* __restrict__ Pa,
                                              float* __restrict__ Pb) {
  int z = blockIdx.z;
  const float* in = z ? in_b : in_a;
  const int* mask = z ? mb : ma;
  unsigned short* o16 = z ? ob : oa;
  float* partial = z ? Pb : Pa;
  int b = blockIdx.y;
  int l0 = blockIdx.x * 32;
  __shared__ int sm[32];
  if (threadIdx.x < 32) sm[threadIdx.x] = mask[b * LSEQ + l0 + threadIdx.x];
  __syncthreads();
  int d = threadIdx.x * 2;
  const float* base = in + ((size_t)b * LSEQ + l0) * DDIM + d;
  unsigned short* obase = o16 + ((size_t)b * LSEQ + l0) * DDIM + d;
  float ax = 0.f, ay = 0.f;
#pragma unroll 4
  for (int r = 0; r < 32; ++r) {
    float2 v = *(const float2*)(base + (size_t)r * DDIM);
    ushort2 u; u.x = f2b(v.x); u.y = f2b(v.y);
    *(ushort2*)(obase + (size_t)r * DDIM) = u;
    if (sm[r] == 0) { ax += v.x; ay += v.y; }
  }
  float2 o; o.x = ax; o.y = ay;
  *(float2*)(partial + ((size_t)(b * 64 + blockIdx.x)) * DDIM + d) = o;
}

// Stage 2 for both inputs: C[b,d] = (1/L)*sum partials. grid 16.
__global__ __launch_bounds__(256) void k_p2(const float* __restrict__ Pa,
                                            const float* __restrict__ Pb,
                                            float* __restrict__ Ca,
                                            float* __restrict__ Cb) {
  int g = blockIdx.x;
  const float* src = (g < 8) ? Pa : Pb;
  float* dst = (g < 8) ? Ca : Cb;
  int b = g & 7;
  int d = threadIdx.x * 2;
  float ax = 0.f, ay = 0.f;
  for (int c = 0; c < 64; ++c) {
    float2 v = *(const float2*)(src + ((size_t)(b * 64 + c)) * DDIM + d);
    ax += v.x; ay += v.y;
  }
  dst[b * DDIM + d] = ax * (1.0f / LSEQ);
  dst[b * DDIM + d + 1] = ay * (1.0f / LSEQ);
}

// Both weights [D,H] f32 -> [H,D] bf16. grid 2048 covers 2x512x512.
__global__ __launch_bounds__(256) void k_transposeW(const float* __restrict__ Wa,
                                                    const float* __restrict__ Wb,
                                                    unsigned short* __restrict__ WaT,
                                                    unsigned short* __restrict__ WbT) {
  int gidx = blockIdx.x * 256 + threadIdx.x;
  const float* W = (gidx < 512 * 512) ? Wa : Wb;
  unsigned short* WT = (gidx < 512 * 512) ? WaT : WbT;
  int idx = gidx & (512 * 512 - 1);
  int h = idx >> 9, d = idx & 511;
  WT[idx] = f2b(W[d * DDIM + h]);
}

// mapped = A(bf16) @ W^T(bf16) + bias -> bf16. 1-D grid 1024, XCD-swizzled:
// the 4 bn-tiles of one (bm,z) get ids = same mod 8 -> same XCD L2 (A-tile shared).
__global__ __launch_bounds__(256) void k_gemm_bias(const unsigned short* __restrict__ a16,
                                                   const unsigned short* __restrict__ b16,
                                                   const unsigned short* __restrict__ WaT,
                                                   const unsigned short* __restrict__ WbT,
                                                   const float* __restrict__ ba,
                                                   const float* __restrict__ bb,
                                                   unsigned short* __restrict__ mapa,
                                                   unsigned short* __restrict__ mapb) {
  int id = blockIdx.x;
  int g = id >> 5, rem = id & 31;
  int bn = (rem >> 3) * 128;
  int f = g * 8 + (rem & 7);   // 0..255
  int bm = (f & 127) * 128;
  int z = f >> 7;
  const unsigned short* A = z ? b16 : a16;
  const unsigned short* Bt = z ? WbT : WaT;
  const float* bias = z ? bb : ba;
  unsigned short* Cout = z ? mapb : mapa;
  __shared__ __align__(16) unsigned short sA[128 * 32], sB[128 * 32];
  f32x4 acc[4][4];
  f32x4 zero = {0.f, 0.f, 0.f, 0.f};
#pragma unroll
  for (int r = 0; r < 4; ++r)
#pragma unroll
    for (int c = 0; c < 4; ++c) acc[r][c] = zero;
  mfma_kloop(A + (size_t)bm * DDIM, Bt + (size_t)bn * DDIM, DDIM, DDIM, DDIM,
             sA, sB, threadIdx.x, acc);
  int wave = threadIdx.x >> 6, lane = threadIdx.x & 63;
  int wm = (wave >> 1) * 64, wn = (wave & 1) * 64, lr = lane & 15, lq = lane >> 4;
#pragma unroll
  for (int r = 0; r < 4; ++r)
#pragma unroll
    for (int c = 0; c < 4; ++c)
#pragma unroll
      for (int rr = 0; rr < 4; ++rr) {
        int row = bm + wm + r * 16 + lq * 4 + rr;
        int col = bn + wn + c * 16 + lr;
        Cout[(size_t)row * DDIM + col] = f2b(acc[r][c][rr] + bias[col]);
      }
}

// E = mask ? exp(scale*mapa.mapb^T) : 0, stored from C-layout (bf16);
// fused row/col sums via shfl butterflies + global atomics.
// 1-D grid 2048, XCD-swizzled: 4x4 (bi,bj) super-tiles colocate on one XCD
// (working set 2x2MB ~= L2).
__global__ __launch_bounds__(256) void k_scores(const unsigned short* __restrict__ mapa,
                                                const unsigned short* __restrict__ mapb,
                                                const int* __restrict__ mask_a,
                                                const int* __restrict__ mask_b,
                                                unsigned short* __restrict__ E,
                                                float* __restrict__ Zrow,
                                                float* __restrict__ Zcol) {
  int id = blockIdx.x;
  int low = id & 7, rest = id >> 3;
  int sub = rest & 15, Ghi = rest >> 4;
  int G = Ghi * 8 + low;         // 0..127
  int b = G >> 4, super = G & 15;
  int bi = (((super >> 2) << 2) + (sub >> 2)) * 128;
  int bj = (((super & 3) << 2) + (sub & 3)) * 128;
  __shared__ __align__(16) unsigned short sA[128 * 32], sB[128 * 32];
  __shared__ int sMa[128], sMb[128];
  int tid = threadIdx.x;
  if (tid < 128)
    sMa[tid] = mask_a[b * LSEQ + bi + tid];
  else
    sMb[tid - 128] = mask_b[b * LSEQ + bj + tid - 128];
  f32x4 acc[4][4];
  f32x4 zero = {0.f, 0.f, 0.f, 0.f};
#pragma unroll
  for (int r = 0; r < 4; ++r)
#pragma unroll
    for (int c = 0; c < 4; ++c) acc[r][c] = zero;
  mfma_kloop(mapa + ((size_t)b * LSEQ + bi) * DDIM, mapb + ((size_t)b * LSEQ + bj) * DDIM,
             DDIM, DDIM, DDIM, sA, sB, tid, acc);
  const float scale = 0.044194173824159216f;  // 1/sqrt(512)
  int wave = tid >> 6, lane = tid & 63;
  int wm = (wave >> 1) * 64, wn = (wave & 1) * 64, lr = lane & 15, lq = lane >> 4;
  unsigned short* Eb = E + (size_t)b * LSEQ * LSEQ + (size_t)bi * LSEQ + bj;
  float colp[4] = {0.f, 0.f, 0.f, 0.f};
  float rowp[4][4];
#pragma unroll
  for (int r = 0; r < 4; ++r) {
#pragma unroll
    for (int rr = 0; rr < 4; ++rr) rowp[r][rr] = 0.f;
#pragma unroll
    for (int c = 0; c < 4; ++c) {
      int jl = wn + c * 16 + lr;
      int mb_ = sMb[jl];
#pragma unroll
      for (int rr = 0; rr < 4; ++rr) {
        int il = wm + r * 16 + lq * 4 + rr;
        float e = (sMa[il] && mb_) ? __expf(acc[r][c][rr] * scale) : 0.f;
        rowp[r][rr] += e;
        colp[c] += e;
        Eb[(size_t)il * LSEQ + jl] = f2b(e);
      }
    }
  }
#pragma unroll
  for (int r = 0; r < 4; ++r)
#pragma unroll
    for (int rr = 0; rr < 4; ++rr) {
      float v = rowp[r][rr];
      v += __shfl_xor(v, 1);
      v += __shfl_xor(v, 2);
      v += __shfl_xor(v, 4);
      v += __shfl_xor(v, 8);
      if (lr == 0) {
        int il = wm + r * 16 + lq * 4 + rr;
        atomicAdd(&Zrow[b * LSEQ + bi + il], v);
      }
    }
#pragma unroll
  for (int c = 0; c < 4; ++c) {
    float v = colp[c];
    v += __shfl_xor(v, 16);
    v += __shfl_xor(v, 32);
    if (lq == 0) atomicAdd(&Zcol[b * LSEQ + bj + wn + c * 16 + lr], v);
  }
}

// out[b,d,i] = (Z[b,i]>0 ? 1/Z[b,i] : 0) * in16[b,i,d], transposed store.
__global__ __launch_bounds__(256) void k_scaleT(const unsigned short* __restrict__ a16,
                                                const unsigned short* __restrict__ b16,
                                                const float* __restrict__ Zrow,
                                                const float* __restrict__ Zcol,
                                                unsigned short* __restrict__ atS,
                                                unsigned short* __restrict__ btS) {
  int zz = blockIdx.z;
  int b = zz & 7, sel = zz >> 3;
  const unsigned short* in = sel ? b16 : a16;
  const float* Z = sel ? Zcol : Zrow;
  unsigned short* out = sel ? btS : atS;
  int i0 = blockIdx.y * 64, d0 = blockIdx.x * 64;
  __shared__ unsigned short lt[64 * 65];
  __shared__ float zinv[64];
  if (threadIdx.x < 64) {
    float z = Z[b * LSEQ + i0 + threadIdx.x];
    zinv[threadIdx.x] = (z > 0.f) ? 1.f / z : 0.f;
  }
  __syncthreads();
  const unsigned short* ib = in + ((size_t)b * LSEQ + i0) * DDIM + d0;
#pragma unroll
  for (int p = 0; p < 16; ++p) {
    int idx = p * 256 + threadIdx.x;
    int dl = idx & 63, il = idx >> 6;
    lt[dl * 65 + il] = f2b(b2f(ib[(size_t)il * DDIM + dl]) * zinv[il]);
  }
  __syncthreads();
  unsigned short* ob = out + ((size_t)b * DDIM + d0) * LSEQ + i0;
#pragma unroll
  for (int p = 0; p < 16; ++p) {
    int idx = p * 256 + threadIdx.x;
    int il = idx & 63, dl = idx >> 6;
    ob[(size_t)dl * LSEQ + il] = lt[dl * 65 + il];
  }
}

// output_a: Out[b,m,d] = (E @ btS^T)[m,d] + addin + Cvec. E k-contiguous (k=j).
// 1-D grid 512, XCD-swizzled: 4 bn-tiles of one (bm,b) share an XCD (E-tile shared).
__global__ __launch_bounds__(256) void k_gemm_out(const unsigned short* __restrict__ Eop,
                                                  const unsigned short* __restrict__ Sop,
                                                  const float* __restrict__ addin,
                                                  const float* __restrict__ Cvec,
                                                  float* __restrict__ Out) {
  int id = blockIdx.x;
  int g = id >> 5, rem = id & 31;
  int bn = (rem >> 3) * 128;
  int f = g * 8 + (rem & 7);   // 0..127
  int bm = (f & 15) * 128;
  int b = f >> 4;
  __shared__ __align__(16) unsigned short sA[128 * 32], sB[128 * 32];
  f32x4 acc[4][4];
  f32x4 zero = {0.f, 0.f, 0.f, 0.f};
#pragma unroll
  for (int r = 0; r < 4; ++r)
#pragma unroll
    for (int c = 0; c < 4; ++c) acc[r][c] = zero;
  mfma_kloop(Eop + (size_t)b * LSEQ * LSEQ + (size_t)bm * LSEQ,
             Sop + (size_t)b * DDIM * LSEQ + (size_t)bn * LSEQ,
             LSEQ, LSEQ, LSEQ, sA, sB, threadIdx.x, acc);
  int wave = threadIdx.x >> 6, lane = threadIdx.x & 63;
  int wm = (wave >> 1) * 64, wn = (wave & 1) * 64, lr = lane & 15, lq = lane >> 4;
#pragma unroll
  for (int r = 0; r < 4; ++r)
#pragma unroll
    for (int c = 0; c < 4; ++c)
#pragma unroll
      for (int rr = 0; rr < 4; ++rr) {
        int row = bm + wm + r * 16 + lq * 4 + rr;
        int col = bn + wn + c * 16 + lr;
        size_t o = ((size_t)b * LSEQ + row) * DDIM + col;
        Out[o] = acc[r][c][rr] + addin[o] + Cvec[b * DDIM + col];
      }
}

// output_b: A = E^T staged via in-kernel transpose (A[m=j][k=i] = E[i][j]).
// LDS writes XOR-swizzled (group ^ (row>>3)&3) to kill the 4-way bank conflict;
// reads apply the same xor and stay single ds_read_b128.
// 1-D grid 512, XCD-swizzled like k_gemm_out.
__global__ __launch_bounds__(256) void k_gemm_outT(const unsigned short* __restrict__ E,
                                                   const unsigned short* __restrict__ Sop,
                                                   const float* __restrict__ addin,
                                                   const float* __restrict__ Cvec,
                                                   float* __restrict__ Out) {
  int id = blockIdx.x;
  int g = id >> 5, rem = id & 31;
  int bn = (rem >> 3) * 128;
  int f = g * 8 + (rem & 7);   // 0..127
  int bm = (f & 15) * 128;     // over Lb(j)
  int b = f >> 4;
  __shared__ __align__(16) unsigned short sA[128 * 32], sB[128 * 32];
  int tid = threadIdx.x;
  const int wave = tid >> 6, lane = tid & 63;
  const int wm = (wave >> 1) * 64, wn = (wave & 1) * 64;
  const int lr = lane & 15, lq = lane >> 4;
  const int srow = tid >> 2, sk = (tid & 3) * 8;
  f32x4 acc[4][4];
  f32x4 zero = {0.f, 0.f, 0.f, 0.f};
#pragma unroll
  for (int r = 0; r < 4; ++r)
#pragma unroll
    for (int c = 0; c < 4; ++c) acc[r][c] = zero;
  unsigned short* dB0 = sB + wave * 512;
  unsigned short* dB1 = sB + 2048 + wave * 512;
  const unsigned short* Bb = Sop + (size_t)b * DDIM * LSEQ + (size_t)bn * LSEQ;
  const unsigned short* pb0 = Bb + (size_t)srow * LSEQ + sk;
  const unsigned short* pb1 = Bb + (size_t)(srow + 64) * LSEQ + sk;
  const int tc = tid & 15;         // u32 k-pair col
  const int tk = tc * 2;
  const int tm = (tid >> 4) * 8;   // m-chunk (j-cols of E)
  const int gq = tc >> 2, wq = tc & 3;
  const unsigned short* pe = E + (size_t)b * LSEQ * LSEQ + (size_t)tk * LSEQ + bm + tm;
  for (int k0 = 0; k0 < LSEQ; k0 += 32) {
    gld16(pb0 + k0, dB0);
    gld16(pb1 + k0, dB1);
    uint4 e0 = *(const uint4*)(pe + (size_t)k0 * LSEQ);
    uint4 e1 = *(const uint4*)(pe + (size_t)k0 * LSEQ + LSEQ);
    unsigned short t0[8], t1[8];
    *(uint4*)t0 = e0; *(uint4*)t1 = e1;
#pragma unroll
    for (int j = 0; j < 8; ++j) {
      int row = tm + j;
      int sw = gq ^ ((row >> 3) & 3);
      unsigned int v = (unsigned int)t0[j] | ((unsigned int)t1[j] << 16);
      *(unsigned int*)(sA + row * 32 + sw * 8 + wq * 2) = v;
    }
    __syncthreads();
    s16x8 af[4], bf[4];
#pragma unroll
    for (int r = 0; r < 4; ++r) {
      int R = wm + r * 16 + lr;
      af[r] = *(const s16x8*)(sA + R * 32 + ((lq ^ ((R >> 3) & 3)) * 8));
    }
#pragma unroll
    for (int c = 0; c < 4; ++c)
      bf[c] = *(const s16x8*)(sB + (wn + c * 16 + lr) * 32 + lq * 8);
#pragma unroll
    for (int r = 0; r < 4; ++r)
#pragma unroll
      for (int c = 0; c < 4; ++c)
        acc[r][c] = __builtin_amdgcn_mfma_f32_16x16x32_bf16(af[r], bf[c], acc[r][c], 0, 0, 0);
    __syncthreads();
  }
#pragma unroll
  for (int r = 0; r < 4; ++r)
#pragma unroll
    for (int c = 0; c < 4; ++c)
#pragma unroll
      for (int rr = 0; rr < 4; ++rr) {
        int row = bm + wm + r * 16 + lq * 4 + rr;
        int col = bn + wn + c * 16 + lr;
        size_t o = ((size_t)b * LSEQ + row) * DDIM + col;
        Out[o] = acc[r][c][rr] + addin[o] + Cvec[b * DDIM + col];
      }
}

extern "C" void kernel_launch(void* const* d_in, const int* in_sizes, int n_in,
                              void* d_out, int out_size, void* d_ws, size_t ws_size,
                              hipStream_t stream) {
  (void)in_sizes; (void)n_in; (void)out_size; (void)ws_size;
  const float* in_a = (const float*)d_in[0];
  const float* in_b = (const float*)d_in[1];
  const int* ma = (const int*)d_in[2];
  const int* mb = (const int*)d_in[3];
  const float* Wa = (const float*)d_in[4];
  const float* ba = (const float*)d_in[5];
  const float* Wb = (const float*)d_in[6];
  const float* bb = (const float*)d_in[7];
  float* out = (float*)d_out;

  char* ws = (char*)d_ws;
  const size_t MB = 1ull << 20;
  unsigned short* a16 = (unsigned short*)(ws + 0 * MB);    // 16MB
  unsigned short* b16 = (unsigned short*)(ws + 16 * MB);   // 16MB
  unsigned short* WaT = (unsigned short*)(ws + 32 * MB);   // 0.5MB
  unsigned short* WbT = (unsigned short*)(ws + 32 * MB + 512 * 1024);
  unsigned short* mapa = (unsigned short*)(ws + 33 * MB);  // 16MB
  unsigned short* mapb = (unsigned short*)(ws + 49 * MB);  // 16MB
  unsigned short* E = (unsigned short*)(ws + 65 * MB);     // 64MB
  unsigned short* atS = (unsigned short*)(ws + 129 * MB);  // 16MB
  unsigned short* btS = (unsigned short*)(ws + 145 * MB);  // 16MB
  float* Zrow = (float*)(ws + 161 * MB);                   // 64KB
  float* Zcol = (float*)(ws + 161 * MB + 65536);           // 64KB
  float* Ca = (float*)(ws + 161 * MB + 2 * 65536);         // 16KB
  float* Cb = (float*)(ws + 161 * MB + 2 * 65536 + 16384); // 16KB
  float* Pa = (float*)(ws + 162 * MB);                     // 1MB
  float* Pb = (float*)(ws + 163 * MB);                     // 1MB

  hipMemsetAsync(Zrow, 0, 2 * 65536, stream);  // Zrow + Zcol
  k_prep<<<dim3(64, 8, 2), 256, 0, stream>>>(in_a, in_b, ma, mb, a16, b16, Pa, Pb);
  k_transposeW<<<2048, 256, 0, stream>>>(Wa, Wb, WaT, WbT);
  k_p2<<<16, 256, 0, stream>>>(Pa, Pb, Ca, Cb);
  k_gemm_bias<<<1024, 256, 0, stream>>>(a16, b16, WaT, WbT, ba, bb, mapa, mapb);
  k_scores<<<2048, 256, 0, stream>>>(mapa, mapb, ma, mb, E, Zrow, Zcol);
  k_scaleT<<<dim3(8, 32, 16), 256, 0, stream>>>(a16, b16, Zrow, Zcol, atS, btS);
  k_gemm_out<<<512, 256, 0, stream>>>(E, btS, in_a, Cb, out);
  k_gemm_outT<<<512, 256, 0, stream>>>(E, atS, in_b, Ca,
                                       out + (size_t)BATCH * LSEQ * DDIM);
}

// Round 6
// 371.220 us; speedup vs baseline: 2.9864x; 1.0191x over previous
//
#include <hip/hip_runtime.h>
#include <hip/hip_bf16.h>

#define BATCH 8
#define LSEQ 2048
#define DDIM 512

using f32x4 = __attribute__((ext_vector_type(4))) float;
using s16x8 = __attribute__((ext_vector_type(8))) short;

static __device__ __forceinline__ unsigned short f2b(float f) {
  __hip_bfloat16 h = __float2bfloat16(f);
  return __builtin_bit_cast(unsigned short, h);
}
static __device__ __forceinline__ float b2f(unsigned short u) {
  unsigned int v = ((unsigned int)u) << 16;
  return __builtin_bit_cast(float, v);
}

// async global->LDS, 16B per lane. LDS dest = wave-uniform base + lane*16.
static __device__ __forceinline__ void gld16(const unsigned short* g, unsigned short* l) {
  __builtin_amdgcn_global_load_lds(
      (__attribute__((address_space(1))) void*)(g),
      (__attribute__((address_space(3))) void*)(l), 16, 0, 0);
}

// 128x128-tile bf16 MFMA K-loop, async staging, row stride 32 (unpadded, required
// by global_load_lds contiguity). 256 threads = 4 waves, 64x64/wave.
__device__ __forceinline__ void mfma_kloop(
    const unsigned short* __restrict__ A, const unsigned short* __restrict__ Bt,
    int K, int lda, int ldb, unsigned short* sA, unsigned short* sB,
    int tid, f32x4 acc[4][4]) {
  const int wave = tid >> 6, lane = tid & 63;
  const int wm = (wave >> 1) * 64, wn = (wave & 1) * 64;
  const int lr = lane & 15, lq = lane >> 4;
  const int srow = tid >> 2;       // 0..63
  const int sk = (tid & 3) * 8;    // 0,8,16,24
  unsigned short* dA0 = sA + wave * 512;          // + implicit lane*8
  unsigned short* dA1 = sA + 2048 + wave * 512;
  unsigned short* dB0 = sB + wave * 512;
  unsigned short* dB1 = sB + 2048 + wave * 512;
  const unsigned short* pa0 = A + (size_t)srow * lda + sk;
  const unsigned short* pa1 = A + (size_t)(srow + 64) * lda + sk;
  const unsigned short* pb0 = Bt + (size_t)srow * ldb + sk;
  const unsigned short* pb1 = Bt + (size_t)(srow + 64) * ldb + sk;
  for (int k0 = 0; k0 < K; k0 += 32) {
    gld16(pa0 + k0, dA0);
    gld16(pa1 + k0, dA1);
    gld16(pb0 + k0, dB0);
    gld16(pb1 + k0, dB1);
    __syncthreads();
    s16x8 af[4], bf[4];
#pragma unroll
    for (int r = 0; r < 4; ++r)
      af[r] = *(const s16x8*)(sA + (wm + r * 16 + lr) * 32 + lq * 8);
#pragma unroll
    for (int c = 0; c < 4; ++c)
      bf[c] = *(const s16x8*)(sB + (wn + c * 16 + lr) * 32 + lq * 8);
#pragma unroll
    for (int r = 0; r < 4; ++r)
#pragma unroll
      for (int c = 0; c < 4; ++c)
        acc[r][c] = __builtin_amdgcn_mfma_f32_16x16x32_bf16(af[r], bf[c], acc[r][c], 0, 0, 0);
    __syncthreads();
  }
}

// Fused f32->bf16 convert + masked partial sum. z selects input a/b.
__global__ __launch_bounds__(256) void k_prep(const float* __restrict__ in_a,
                                              const float* __restrict__ in_b,
                                              const int* __restrict__ ma,
                                              const int* __restrict__ mb,
                                              unsigned short* __restrict__ oa,
                                              unsigned short* __restrict__ ob,
                                              float* __restrict__ Pa,
                                              float* __restrict__ Pb) {
  int z = blockIdx.z;
  const float* in = z ? in_b : in_a;
  const int* mask = z ? mb : ma;
  unsigned short* o16 = z ? ob : oa;
  float* partial = z ? Pb : Pa;
  int b = blockIdx.y;
  int l0 = blockIdx.x * 32;
  __shared__ int sm[32];
  if (threadIdx.x < 32) sm[threadIdx.x] = mask[b * LSEQ + l0 + threadIdx.x];
  __syncthreads();
  int d = threadIdx.x * 2;
  const float* base = in + ((size_t)b * LSEQ + l0) * DDIM + d;
  unsigned short* obase = o16 + ((size_t)b * LSEQ + l0) * DDIM + d;
  float ax = 0.f, ay = 0.f;
#pragma unroll 4
  for (int r = 0; r < 32; ++r) {
    float2 v = *(const float2*)(base + (size_t)r * DDIM);
    ushort2 u; u.x = f2b(v.x); u.y = f2b(v.y);
    *(ushort2*)(obase + (size_t)r * DDIM) = u;
    if (sm[r] == 0) { ax += v.x; ay += v.y; }
  }
  float2 o; o.x = ax; o.y = ay;
  *(float2*)(partial + ((size_t)(b * 64 + blockIdx.x)) * DDIM + d) = o;
}

// Stage 2 for both inputs: C[b,d] = (1/L)*sum partials. grid 16.
__global__ __launch_bounds__(256) void k_p2(const float* __restrict__ Pa,
                                            const float* __restrict__ Pb,
                                            float* __restrict__ Ca,
                                            float* __restrict__ Cb) {
  int g = blockIdx.x;
  const float* src = (g < 8) ? Pa : Pb;
  float* dst = (g < 8) ? Ca : Cb;
  int b = g & 7;
  int d = threadIdx.x * 2;
  float ax = 0.f, ay = 0.f;
  for (int c = 0; c < 64; ++c) {
    float2 v = *(const float2*)(src + ((size_t)(b * 64 + c)) * DDIM + d);
    ax += v.x; ay += v.y;
  }
  dst[b * DDIM + d] = ax * (1.0f / LSEQ);
  dst[b * DDIM + d + 1] = ay * (1.0f / LSEQ);
}

// Both weights [D,H] f32 -> [H,D] bf16. grid 2048 covers 2x512x512.
__global__ __launch_bounds__(256) void k_transposeW(const float* __restrict__ Wa,
                                                    const float* __restrict__ Wb,
                                                    unsigned short* __restrict__ WaT,
                                                    unsigned short* __restrict__ WbT) {
  int gidx = blockIdx.x * 256 + threadIdx.x;
  const float* W = (gidx < 512 * 512) ? Wa : Wb;
  unsigned short* WT = (gidx < 512 * 512) ? WaT : WbT;
  int idx = gidx & (512 * 512 - 1);
  int h = idx >> 9, d = idx & 511;
  WT[idx] = f2b(W[d * DDIM + h]);
}

// mapped = A(bf16) @ W^T(bf16) + bias -> bf16. 1-D grid 1024, XCD-swizzled.
__global__ __launch_bounds__(256) void k_gemm_bias(const unsigned short* __restrict__ a16,
                                                   const unsigned short* __restrict__ b16,
                                                   const unsigned short* __restrict__ WaT,
                                                   const unsigned short* __restrict__ WbT,
                                                   const float* __restrict__ ba,
                                                   const float* __restrict__ bb,
                                                   unsigned short* __restrict__ mapa,
                                                   unsigned short* __restrict__ mapb) {
  int id = blockIdx.x;
  int g = id >> 5, rem = id & 31;
  int bn = (rem >> 3) * 128;
  int f = g * 8 + (rem & 7);   // 0..255
  int bm = (f & 127) * 128;
  int z = f >> 7;
  const unsigned short* A = z ? b16 : a16;
  const unsigned short* Bt = z ? WbT : WaT;
  const float* bias = z ? bb : ba;
  unsigned short* Cout = z ? mapb : mapa;
  __shared__ __align__(16) unsigned short sA[128 * 32], sB[128 * 32];
  f32x4 acc[4][4];
  f32x4 zero = {0.f, 0.f, 0.f, 0.f};
#pragma unroll
  for (int r = 0; r < 4; ++r)
#pragma unroll
    for (int c = 0; c < 4; ++c) acc[r][c] = zero;
  mfma_kloop(A + (size_t)bm * DDIM, Bt + (size_t)bn * DDIM, DDIM, DDIM, DDIM,
             sA, sB, threadIdx.x, acc);
  int wave = threadIdx.x >> 6, lane = threadIdx.x & 63;
  int wm = (wave >> 1) * 64, wn = (wave & 1) * 64, lr = lane & 15, lq = lane >> 4;
#pragma unroll
  for (int r = 0; r < 4; ++r)
#pragma unroll
    for (int c = 0; c < 4; ++c)
#pragma unroll
      for (int rr = 0; rr < 4; ++rr) {
        int row = bm + wm + r * 16 + lq * 4 + rr;
        int col = bn + wn + c * 16 + lr;
        Cout[(size_t)row * DDIM + col] = f2b(acc[r][c][rr] + bias[col]);
      }
}

// E = mask ? exp(scale*mapa.mapb^T) : 0, stored from C-layout (bf16);
// fused row/col sums via shfl butterflies + global atomics.
// 1-D grid 2048, XCD-swizzled: 4x4 (bi,bj) super-tiles colocate on one XCD.
__global__ __launch_bounds__(256) void k_scores(const unsigned short* __restrict__ mapa,
                                                const unsigned short* __restrict__ mapb,
                                                const int* __restrict__ mask_a,
                                                const int* __restrict__ mask_b,
                                                unsigned short* __restrict__ E,
                                                float* __restrict__ Zrow,
                                                float* __restrict__ Zcol) {
  int id = blockIdx.x;
  int low = id & 7, rest = id >> 3;
  int sub = rest & 15, Ghi = rest >> 4;
  int G = Ghi * 8 + low;         // 0..127
  int b = G >> 4, super = G & 15;
  int bi = (((super >> 2) << 2) + (sub >> 2)) * 128;
  int bj = (((super & 3) << 2) + (sub & 3)) * 128;
  __shared__ __align__(16) unsigned short sA[128 * 32], sB[128 * 32];
  __shared__ int sMa[128], sMb[128];
  int tid = threadIdx.x;
  if (tid < 128)
    sMa[tid] = mask_a[b * LSEQ + bi + tid];
  else
    sMb[tid - 128] = mask_b[b * LSEQ + bj + tid - 128];
  f32x4 acc[4][4];
  f32x4 zero = {0.f, 0.f, 0.f, 0.f};
#pragma unroll
  for (int r = 0; r < 4; ++r)
#pragma unroll
    for (int c = 0; c < 4; ++c) acc[r][c] = zero;
  mfma_kloop(mapa + ((size_t)b * LSEQ + bi) * DDIM, mapb + ((size_t)b * LSEQ + bj) * DDIM,
             DDIM, DDIM, DDIM, sA, sB, tid, acc);
  const float scale = 0.044194173824159216f;  // 1/sqrt(512)
  int wave = tid >> 6, lane = tid & 63;
  int wm = (wave >> 1) * 64, wn = (wave & 1) * 64, lr = lane & 15, lq = lane >> 4;
  unsigned short* Eb = E + (size_t)b * LSEQ * LSEQ + (size_t)bi * LSEQ + bj;
  float colp[4] = {0.f, 0.f, 0.f, 0.f};
  float rowp[4][4];
#pragma unroll
  for (int r = 0; r < 4; ++r) {
#pragma unroll
    for (int rr = 0; rr < 4; ++rr) rowp[r][rr] = 0.f;
#pragma unroll
    for (int c = 0; c < 4; ++c) {
      int jl = wn + c * 16 + lr;
      int mb_ = sMb[jl];
#pragma unroll
      for (int rr = 0; rr < 4; ++rr) {
        int il = wm + r * 16 + lq * 4 + rr;
        float e = (sMa[il] && mb_) ? __expf(acc[r][c][rr] * scale) : 0.f;
        rowp[r][rr] += e;
        colp[c] += e;
        Eb[(size_t)il * LSEQ + jl] = f2b(e);
      }
    }
  }
#pragma unroll
  for (int r = 0; r < 4; ++r)
#pragma unroll
    for (int rr = 0; rr < 4; ++rr) {
      float v = rowp[r][rr];
      v += __shfl_xor(v, 1);
      v += __shfl_xor(v, 2);
      v += __shfl_xor(v, 4);
      v += __shfl_xor(v, 8);
      if (lr == 0) {
        int il = wm + r * 16 + lq * 4 + rr;
        atomicAdd(&Zrow[b * LSEQ + bi + il], v);
      }
    }
#pragma unroll
  for (int c = 0; c < 4; ++c) {
    float v = colp[c];
    v += __shfl_xor(v, 16);
    v += __shfl_xor(v, 32);
    if (lq == 0) atomicAdd(&Zcol[b * LSEQ + bj + wn + c * 16 + lr], v);
  }
}

// out[b,d,i] = (Z[b,i]>0 ? 1/Z[b,i] : 0) * in16[b,i,d], transposed store.
__global__ __launch_bounds__(256) void k_scaleT(const unsigned short* __restrict__ a16,
                                                const unsigned short* __restrict__ b16,
                                                const float* __restrict__ Zrow,
                                                const float* __restrict__ Zcol,
                                                unsigned short* __restrict__ atS,
                                                unsigned short* __restrict__ btS) {
  int zz = blockIdx.z;
  int b = zz & 7, sel = zz >> 3;
  const unsigned short* in = sel ? b16 : a16;
  const float* Z = sel ? Zcol : Zrow;
  unsigned short* out = sel ? btS : atS;
  int i0 = blockIdx.y * 64, d0 = blockIdx.x * 64;
  __shared__ unsigned short lt[64 * 65];
  __shared__ float zinv[64];
  if (threadIdx.x < 64) {
    float z = Z[b * LSEQ + i0 + threadIdx.x];
    zinv[threadIdx.x] = (z > 0.f) ? 1.f / z : 0.f;
  }
  __syncthreads();
  const unsigned short* ib = in + ((size_t)b * LSEQ + i0) * DDIM + d0;
#pragma unroll
  for (int p = 0; p < 16; ++p) {
    int idx = p * 256 + threadIdx.x;
    int dl = idx & 63, il = idx >> 6;
    lt[dl * 65 + il] = f2b(b2f(ib[(size_t)il * DDIM + dl]) * zinv[il]);
  }
  __syncthreads();
  unsigned short* ob = out + ((size_t)b * DDIM + d0) * LSEQ + i0;
#pragma unroll
  for (int p = 0; p < 16; ++p) {
    int idx = p * 256 + threadIdx.x;
    int il = idx & 63, dl = idx >> 6;
    ob[(size_t)dl * LSEQ + il] = lt[dl * 65 + il];
  }
}

// Merged output GEMMs: grid 1024 (4 blocks/CU).
//   ids [0,512):   output_a = E @ btS^T + a16 + Cb          (A k-contiguous)
//   ids [512,1024): output_b = E^T @ atS^T + b16 + Ca       (A transposed in-kernel)
// Per-half XCD swizzle: the 4 bn tiles of one (bm,b) share an XCD (E-tile reuse).
__global__ __launch_bounds__(256) void k_gemm_outs(const unsigned short* __restrict__ E,
                                                   const unsigned short* __restrict__ btS,
                                                   const unsigned short* __restrict__ atS,
                                                   const unsigned short* __restrict__ a16,
                                                   const unsigned short* __restrict__ b16,
                                                   const float* __restrict__ Ca,
                                                   const float* __restrict__ Cb,
                                                   float* __restrict__ OutA,
                                                   float* __restrict__ OutB) {
  int id0 = blockIdx.x;
  int modeT = id0 >> 9;          // 0: output_a, 1: output_b
  int id = id0 & 511;
  int g = id >> 5, rem = id & 31;
  int bn = (rem >> 3) * 128;
  int f = g * 8 + (rem & 7);     // 0..127
  int bm = (f & 15) * 128;
  int b = f >> 4;
  const unsigned short* Sop = modeT ? atS : btS;
  const unsigned short* addin = modeT ? b16 : a16;
  const float* Cvec = modeT ? Ca : Cb;
  float* Out = modeT ? OutB : OutA;

  __shared__ __align__(16) unsigned short sA[128 * 32], sB[128 * 32];
  int tid = threadIdx.x;
  const int wave = tid >> 6, lane = tid & 63;
  const int wm = (wave >> 1) * 64, wn = (wave & 1) * 64;
  const int lr = lane & 15, lq = lane >> 4;
  f32x4 acc[4][4];
  f32x4 zero = {0.f, 0.f, 0.f, 0.f};
#pragma unroll
  for (int r = 0; r < 4; ++r)
#pragma unroll
    for (int c = 0; c < 4; ++c) acc[r][c] = zero;

  if (!modeT) {
    mfma_kloop(E + (size_t)b * LSEQ * LSEQ + (size_t)bm * LSEQ,
               Sop + (size_t)b * DDIM * LSEQ + (size_t)bn * LSEQ,
               LSEQ, LSEQ, LSEQ, sA, sB, tid, acc);
  } else {
    const int srow = tid >> 2, sk = (tid & 3) * 8;
    unsigned short* dB0 = sB + wave * 512;
    unsigned short* dB1 = sB + 2048 + wave * 512;
    const unsigned short* Bb = Sop + (size_t)b * DDIM * LSEQ + (size_t)bn * LSEQ;
    const unsigned short* pb0 = Bb + (size_t)srow * LSEQ + sk;
    const unsigned short* pb1 = Bb + (size_t)(srow + 64) * LSEQ + sk;
    const int tc = tid & 15;         // u32 k-pair col
    const int tk = tc * 2;
    const int tm = (tid >> 4) * 8;   // m-chunk (j-cols of E)
    const int gq = tc >> 2, wq = tc & 3;
    const unsigned short* pe = E + (size_t)b * LSEQ * LSEQ + (size_t)tk * LSEQ + bm + tm;
    for (int k0 = 0; k0 < LSEQ; k0 += 32) {
      gld16(pb0 + k0, dB0);
      gld16(pb1 + k0, dB1);
      uint4 e0 = *(const uint4*)(pe + (size_t)k0 * LSEQ);
      uint4 e1 = *(const uint4*)(pe + (size_t)k0 * LSEQ + LSEQ);
      unsigned short t0[8], t1[8];
      *(uint4*)t0 = e0; *(uint4*)t1 = e1;
#pragma unroll
      for (int j = 0; j < 8; ++j) {
        int row = tm + j;
        int sw = gq ^ ((row >> 3) & 3);
        unsigned int v = (unsigned int)t0[j] | ((unsigned int)t1[j] << 16);
        *(unsigned int*)(sA + row * 32 + sw * 8 + wq * 2) = v;
      }
      __syncthreads();
      s16x8 af[4], bf[4];
#pragma unroll
      for (int r = 0; r < 4; ++r) {
        int R = wm + r * 16 + lr;
        af[r] = *(const s16x8*)(sA + R * 32 + ((lq ^ ((R >> 3) & 3)) * 8));
      }
#pragma unroll
      for (int c = 0; c < 4; ++c)
        bf[c] = *(const s16x8*)(sB + (wn + c * 16 + lr) * 32 + lq * 8);
#pragma unroll
      for (int r = 0; r < 4; ++r)
#pragma unroll
        for (int c = 0; c < 4; ++c)
          acc[r][c] = __builtin_amdgcn_mfma_f32_16x16x32_bf16(af[r], bf[c], acc[r][c], 0, 0, 0);
      __syncthreads();
    }
  }

#pragma unroll
  for (int r = 0; r < 4; ++r)
#pragma unroll
    for (int c = 0; c < 4; ++c)
#pragma unroll
      for (int rr = 0; rr < 4; ++rr) {
        int row = bm + wm + r * 16 + lq * 4 + rr;
        int col = bn + wn + c * 16 + lr;
        size_t o = ((size_t)b * LSEQ + row) * DDIM + col;
        Out[o] = acc[r][c][rr] + b2f(addin[o]) + Cvec[b * DDIM + col];
      }
}

extern "C" void kernel_launch(void* const* d_in, const int* in_sizes, int n_in,
                              void* d_out, int out_size, void* d_ws, size_t ws_size,
                              hipStream_t stream) {
  (void)in_sizes; (void)n_in; (void)out_size; (void)ws_size;
  const float* in_a = (const float*)d_in[0];
  const float* in_b = (const float*)d_in[1];
  const int* ma = (const int*)d_in[2];
  const int* mb = (const int*)d_in[3];
  const float* Wa = (const float*)d_in[4];
  const float* ba = (const float*)d_in[5];
  const float* Wb = (const float*)d_in[6];
  const float* bb = (const float*)d_in[7];
  float* out = (float*)d_out;

  char* ws = (char*)d_ws;
  const size_t MB = 1ull << 20;
  unsigned short* a16 = (unsigned short*)(ws + 0 * MB);    // 16MB
  unsigned short* b16 = (unsigned short*)(ws + 16 * MB);   // 16MB
  unsigned short* WaT = (unsigned short*)(ws + 32 * MB);   // 0.5MB
  unsigned short* WbT = (unsigned short*)(ws + 32 * MB + 512 * 1024);
  unsigned short* mapa = (unsigned short*)(ws + 33 * MB);  // 16MB
  unsigned short* mapb = (unsigned short*)(ws + 49 * MB);  // 16MB
  unsigned short* E = (unsigned short*)(ws + 65 * MB);     // 64MB
  unsigned short* atS = (unsigned short*)(ws + 129 * MB);  // 16MB
  unsigned short* btS = (unsigned short*)(ws + 145 * MB);  // 16MB
  float* Zrow = (float*)(ws + 161 * MB);                   // 64KB
  float* Zcol = (float*)(ws + 161 * MB + 65536);           // 64KB
  float* Ca = (float*)(ws + 161 * MB + 2 * 65536);         // 16KB
  float* Cb = (float*)(ws + 161 * MB + 2 * 65536 + 16384); // 16KB
  float* Pa = (float*)(ws + 162 * MB);                     // 1MB
  float* Pb = (float*)(ws + 163 * MB);                     // 1MB

  hipMemsetAsync(Zrow, 0, 2 * 65536, stream);  // Zrow + Zcol
  k_prep<<<dim3(64, 8, 2), 256, 0, stream>>>(in_a, in_b, ma, mb, a16, b16, Pa, Pb);
  k_transposeW<<<2048, 256, 0, stream>>>(Wa, Wb, WaT, WbT);
  k_p2<<<16, 256, 0, stream>>>(Pa, Pb, Ca, Cb);
  k_gemm_bias<<<1024, 256, 0, stream>>>(a16, b16, WaT, WbT, ba, bb, mapa, mapb);
  k_scores<<<2048, 256, 0, stream>>>(mapa, mapb, ma, mb, E, Zrow, Zcol);
  k_scaleT<<<dim3(8, 32, 16), 256, 0, stream>>>(a16, b16, Zrow, Zcol, atS, btS);
  k_gemm_outs<<<1024, 256, 0, stream>>>(E, btS, atS, a16, b16, Ca, Cb,
                                        out, out + (size_t)BATCH * LSEQ * DDIM);
}